// Round 6
// baseline (2756.054 us; speedup 1.0000x reference)
//
#include <hip/hip_runtime.h>

#define LNUM 6
#define EDIM 1024
#define HNUM 8
#define DHD  128
#define RNUM 33
#define FFD  4096
#define BNUM 8
#define SLEN 512
#define TOK  (BNUM*SLEN)   // 4096

typedef __attribute__((ext_vector_type(8))) short bf16x8;
typedef __attribute__((ext_vector_type(4))) float f32x4;
typedef unsigned short u16;
typedef unsigned int u32;

__device__ __forceinline__ u16 f2b(float f) {
  u32 u = __builtin_bit_cast(u32, f);
  u32 r = u + 0x7FFFu + ((u >> 16) & 1u);
  return (u16)(r >> 16);
}
__device__ __forceinline__ float blo(u32 p) { return __builtin_bit_cast(float, p << 16); }
__device__ __forceinline__ float bhi(u32 p) { return __builtin_bit_cast(float, p & 0xFFFF0000u); }
__device__ __forceinline__ u32 pck(float a, float b) { return (u32)f2b(a) | ((u32)f2b(b) << 16); }

// async global->LDS, 16B per lane. LDS dest is wave-uniform base + lane*16.
#define GL16(gp, lp) __builtin_amdgcn_global_load_lds(                        \
    (const __attribute__((address_space(1))) void*)(gp),                      \
    (__attribute__((address_space(3))) void*)(lp), 16, 0, 0)

// ---------------- LayerNorm ----------------
template<int BF16OUT>
__global__ __launch_bounds__(256) void ln_kernel(const float* __restrict__ x,
                                                 const float* __restrict__ g,
                                                 const float* __restrict__ be,
                                                 void* __restrict__ o) {
  int row = blockIdx.x;
  int t = threadIdx.x;
  const float* xr = x + (size_t)row * EDIM;
  float4 xv = *reinterpret_cast<const float4*>(xr + t * 4);
  float s1 = xv.x + xv.y + xv.z + xv.w;
  float s2 = xv.x*xv.x + xv.y*xv.y + xv.z*xv.z + xv.w*xv.w;
#pragma unroll
  for (int off = 32; off >= 1; off >>= 1) {
    s1 += __shfl_down(s1, off, 64);
    s2 += __shfl_down(s2, off, 64);
  }
  __shared__ float r1[4], r2[4];
  if ((t & 63) == 0) { r1[t >> 6] = s1; r2[t >> 6] = s2; }
  __syncthreads();
  s1 = r1[0] + r1[1] + r1[2] + r1[3];
  s2 = r2[0] + r2[1] + r2[2] + r2[3];
  float mean = s1 * (1.0f / EDIM);
  float var  = s2 * (1.0f / EDIM) - mean * mean;
  float rstd = rsqrtf(var + 1e-5f);
  float4 gv = *reinterpret_cast<const float4*>(g + t * 4);
  float4 bv = *reinterpret_cast<const float4*>(be + t * 4);
  float o0 = (xv.x - mean) * rstd * gv.x + bv.x;
  float o1 = (xv.y - mean) * rstd * gv.y + bv.y;
  float o2 = (xv.z - mean) * rstd * gv.z + bv.z;
  float o3 = (xv.w - mean) * rstd * gv.w + bv.w;
  if (BF16OUT) {
    ushort4 ov; ov.x = f2b(o0); ov.y = f2b(o1); ov.z = f2b(o2); ov.w = f2b(o3);
    *reinterpret_cast<ushort4*>((u16*)o + (size_t)row * EDIM + t * 4) = ov;
  } else {
    *reinterpret_cast<float4*>((float*)o + (size_t)row * EDIM + t * 4) = make_float4(o0, o1, o2, o3);
  }
}

// ---------------- Weight transpose: f32 [Kd][Nd] -> bf16 [Nd][Kd] ----------------
__global__ __launch_bounds__(256) void wtrans(const float* __restrict__ src0,
                                              u16* __restrict__ dst0,
                                              int Kd, int Nd, size_t sstride, size_t dstride) {
  __shared__ float Ts[32][33];
  const float* src = src0 + blockIdx.z * sstride;
  u16* dst = dst0 + blockIdx.z * dstride;
  int r0 = blockIdx.y * 32, c0 = blockIdx.x * 32;
  int ty = threadIdx.x >> 3, tx = threadIdx.x & 7;
  float4 v = *reinterpret_cast<const float4*>(src + (size_t)(r0 + ty) * Nd + c0 + tx * 4);
  Ts[ty][tx*4+0] = v.x; Ts[ty][tx*4+1] = v.y; Ts[ty][tx*4+2] = v.z; Ts[ty][tx*4+3] = v.w;
  __syncthreads();
  ushort4 o;
  o.x = f2b(Ts[tx*4+0][ty]); o.y = f2b(Ts[tx*4+1][ty]);
  o.z = f2b(Ts[tx*4+2][ty]); o.w = f2b(Ts[tx*4+3][ty]);
  *reinterpret_cast<ushort4*>(dst + (size_t)(c0 + ty) * Kd + r0 + tx * 4) = o;
}

// ---------------- bf16 MFMA GEMM: C[M,N] = A[M,K] @ B[N,K]^T ----------------
template<int BIASMODE, int ACT, int RES, int OUTBF16>
__global__ __launch_bounds__(256) void gemm_bt(const u16* __restrict__ A,
                                               const u16* __restrict__ B,
                                               const float* __restrict__ bias0,
                                               const float* __restrict__ bias1,
                                               const float* __restrict__ res,
                                               void* __restrict__ Cv,
                                               int M, int N, int K) {
  __shared__ u16 As[128 * 64];
  __shared__ u16 Bs[128 * 64];
  int t = threadIdx.x;
  int l = t & 63, w = t >> 6;
  int wm = w & 1, wn = w >> 1;
  int m0 = blockIdx.y * 128, n0 = blockIdx.x * 128;
  f32x4 acc[4][4] = {};
  const u16* Agp = A + (size_t)(m0 + w * 32 + (l >> 3)) * K + (l & 7) * 8;
  const u16* Bgp = B + (size_t)(n0 + w * 32 + (l >> 3)) * K + (l & 7) * 8;
  u16* Alp = As + w * 4 * 512;
  u16* Blp = Bs + w * 4 * 512;
  for (int k0 = 0; k0 < K; k0 += 64) {
    __syncthreads();
#pragma unroll
    for (int u = 0; u < 4; ++u) {
      GL16(Agp + (size_t)(u * 8) * K + k0, Alp + u * 512);
      GL16(Bgp + (size_t)(u * 8) * K + k0, Blp + u * 512);
    }
    __syncthreads();
#pragma unroll
    for (int d4 = 0; d4 < 2; ++d4) {
      bf16x8 af[4];
#pragma unroll
      for (int fm = 0; fm < 4; ++fm) {
        int row = wm * 64 + fm * 16 + (l & 15);
        af[fm] = *reinterpret_cast<const bf16x8*>(As + row * 64 + (d4 * 4 + (l >> 4)) * 8);
      }
#pragma unroll
      for (int fn = 0; fn < 4; ++fn) {
        int row = wn * 64 + fn * 16 + (l & 15);
        bf16x8 bf = *reinterpret_cast<const bf16x8*>(Bs + row * 64 + (d4 * 4 + (l >> 4)) * 8);
#pragma unroll
        for (int fm = 0; fm < 4; ++fm)
          acc[fm][fn] = __builtin_amdgcn_mfma_f32_16x16x32_bf16(af[fm], bf, acc[fm][fn], 0, 0, 0);
      }
    }
  }
#pragma unroll
  for (int fm = 0; fm < 4; ++fm)
#pragma unroll
    for (int fn = 0; fn < 4; ++fn)
#pragma unroll
      for (int e = 0; e < 4; ++e) {
        int m = m0 + wm * 64 + fm * 16 + (l >> 4) * 4 + e;
        int n = n0 + wn * 64 + fn * 16 + (l & 15);
        float v = acc[fm][fn][e];
        if (BIASMODE == 0) v += bias0[n];
        if (BIASMODE == 1) v += bias0[m];
        if (BIASMODE == 2) v += (n < 1024) ? bias0[n] : bias1[n - 1024];
        if (ACT == 1) v = fmaxf(v, 0.f);
        if (RES == 1) v += res[(size_t)m * N + n];
        if (OUTBF16) ((u16*)Cv)[(size_t)m * N + n] = f2b(v);
        else ((float*)Cv)[(size_t)m * N + n] = v;
      }
}

// ---------------- Relational attention (flash-style online softmax) ----------------
// Block = (b, h, 64-q-rows); wave w owns q-rows [w*16, w*16+16). 4 KV tiles of 128.
// LDS 67840 B -> 2 blocks/CU (vs 136 KB / 1 block before).
#define A_KV 0        // 32768: relk[48][128] -> K/V [128][128] swz -> relvT [128][64]
#define A_PS 32768    // 16384: per-wave 4096B slabs: P[16][128] swz / arelB / out-stage
#define A_QR 49152    // 9216: qr f32 [64][36]
#define A_AR 58368    // 9216: AREL f32 [64][36] (wave-private rows)
#define A_LS 67584    // 256 : LSUM f32 [64]
#define A_SM 67840

__global__ __launch_bounds__(256) void attn_kernel(const u16* __restrict__ qk,
                                                   const u16* __restrict__ vt,
                                                   const int* __restrict__ rel,
                                                   const int* __restrict__ lens,
                                                   const float* __restrict__ relk,
                                                   const float* __restrict__ relv,
                                                   u16* __restrict__ outb) {
  __align__(16) __shared__ char sm[A_SM];
  char*  KV  = sm + A_KV;
  char*  PSb = sm + A_PS;
  float* QR  = (float*)(sm + A_QR);
  float* AREL = (float*)(sm + A_AR);
  float* LSUM = (float*)(sm + A_LS);

  const int t = threadIdx.x;
  const int l = t & 63, w = t >> 6;
  const int lg = l >> 4;        // 0..3 (row group)
  const int ll = l & 15;        // 0..15 (col within fragment)
  const int bx = blockIdx.x;
  const int it = bx & 7, hh = (bx >> 3) & 7, b = bx >> 6;
  const int i0 = it * 64;
  const int len = lens[b];
  const float scale = 0.08838834764831845f;
  char* PSw = PSb + w * 4096;   // own P slab

  // zero own AREL rows (wave-private, no barrier needed for these later)
  for (int idx = l; idx < 16 * 36; idx += 64) AREL[w * 16 * 36 + idx] = 0.f;
  // stage relk bf16 [48][128] swizzled (rows>=33 zero) into KV
  if (t < 192) {
    int r = t >> 2, sub = t & 3;
#pragma unroll
    for (int u = 0; u < 4; ++u) {
      int seg = sub * 4 + u;
      uint4 o;
      if (r < RNUM) {
        float4 f0 = *reinterpret_cast<const float4*>(relk + r * DHD + seg * 8);
        float4 f1 = *reinterpret_cast<const float4*>(relk + r * DHD + seg * 8 + 4);
        o.x = pck(f0.x, f0.y); o.y = pck(f0.z, f0.w);
        o.z = pck(f1.x, f1.y); o.w = pck(f1.z, f1.w);
      } else { o.x = o.y = o.z = o.w = 0u; }
      *reinterpret_cast<uint4*>(KV + r * 256 + ((seg * 16) ^ ((r & 7) << 4))) = o;
    }
  }
  // Q fragments: rows w*16+ll, direct global->reg (used for qr AND QK)
  bf16x8 aq[4];
  {
    const u16* qrow = qk + (size_t)(b * SLEN + i0 + w * 16 + ll) * 2048 + hh * DHD;
#pragma unroll
    for (int d4 = 0; d4 < 4; ++d4)
      aq[d4] = *reinterpret_cast<const bf16x8*>(qrow + (d4 * 4 + lg) * 8);
  }
  __syncthreads();
  // qr = Q @ relk^T -> QR[64][36] (own-wave rows; read later by same wave only)
#pragma unroll
  for (int rb = 0; rb < 3; ++rb) {
    f32x4 acc = {};
#pragma unroll
    for (int d4 = 0; d4 < 4; ++d4) {
      int rr = rb * 16 + ll;
      bf16x8 br = *reinterpret_cast<const bf16x8*>(KV + rr * 256 + (((d4 * 4 + lg) * 16) ^ ((rr & 7) << 4)));
      acc = __builtin_amdgcn_mfma_f32_16x16x32_bf16(aq[d4], br, acc, 0, 0, 0);
    }
    int col = rb * 16 + ll;
    if (col < 36)
#pragma unroll
      for (int e = 0; e < 4; ++e)
        QR[(w * 16 + lg * 4 + e) * 36 + col] = acc[e];
  }

  float m_[4], ls_[4];
#pragma unroll
  for (int e = 0; e < 4; ++e) { m_[e] = -3.0e38f; ls_[e] = 0.f; }
  f32x4 oacc[8] = {};

  for (int kt = 0; kt < 4; ++kt) {
    __syncthreads();            // KV free (prev readers done)
    { // stage K(kt): rows j=key, cols d, swizzled
      int j = t >> 1, half = t & 1;
      const u16* src = qk + (size_t)(b * SLEN + kt * 128 + j) * 2048 + 1024 + hh * DHD;
#pragma unroll
      for (int u = 0; u < 8; ++u) {
        int c = half * 8 + u;
        *reinterpret_cast<uint4*>(KV + j * 256 + ((c * 16) ^ ((j & 7) << 4))) =
            *reinterpret_cast<const uint4*>(src + c * 8);
      }
    }
    __syncthreads();
    // QK^T: 16 rows x 128 keys per wave
    f32x4 sacc[8];
#pragma unroll
    for (int fj = 0; fj < 8; ++fj) {
      f32x4 a = {};
#pragma unroll
      for (int d4 = 0; d4 < 4; ++d4) {
        int row = fj * 16 + ll;
        bf16x8 bk_ = *reinterpret_cast<const bf16x8*>(KV + row * 256 + (((d4 * 4 + lg) * 16) ^ ((row & 7) << 4)));
        a = __builtin_amdgcn_mfma_f32_16x16x32_bf16(aq[d4], bk_, a, 0, 0, 0);
      }
      sacc[fj] = a;
    }
    // + qr[rel], scale, mask; per-row tile max
    int rr_[8][4];
    float pmax[4] = {-3.0e38f, -3.0e38f, -3.0e38f, -3.0e38f};
    const int* relrow0 = rel + ((size_t)(b * SLEN + i0 + w * 16 + lg * 4)) * SLEN + kt * 128 + ll;
#pragma unroll
    for (int fj = 0; fj < 8; ++fj)
#pragma unroll
      for (int e = 0; e < 4; ++e) {
        int iloc = lg * 4 + e;
        int r = relrow0[(size_t)e * SLEN + fj * 16];
        rr_[fj][e] = r;
        float s = (sacc[fj][e] + QR[(w * 16 + iloc) * 36 + r]) * scale;
        if (i0 + w * 16 + iloc >= len || kt * 128 + fj * 16 + ll >= len) s = -1e9f;
        sacc[fj][e] = s;
        pmax[e] = fmaxf(pmax[e], s);
      }
#pragma unroll
    for (int e = 0; e < 4; ++e) {
      pmax[e] = fmaxf(pmax[e], __shfl_xor(pmax[e], 1, 64));
      pmax[e] = fmaxf(pmax[e], __shfl_xor(pmax[e], 2, 64));
      pmax[e] = fmaxf(pmax[e], __shfl_xor(pmax[e], 4, 64));
      pmax[e] = fmaxf(pmax[e], __shfl_xor(pmax[e], 8, 64));
    }
    // online-softmax update
    float f_[4];
#pragma unroll
    for (int e = 0; e < 4; ++e) {
      float mn = fmaxf(m_[e], pmax[e]);
      f_[e] = __expf(m_[e] - mn);
      m_[e] = mn;
      ls_[e] *= f_[e];
    }
#pragma unroll
    for (int fd = 0; fd < 8; ++fd)
#pragma unroll
      for (int e = 0; e < 4; ++e) oacc[fd][e] *= f_[e];
    // rescale AREL rows (16 lanes split 33 bins; rows wave-private, in-order vs own atomics)
#pragma unroll
    for (int e = 0; e < 4; ++e) {
      if (f_[e] != 1.0f) {
        int row = w * 16 + lg * 4 + e;
        AREL[row * 36 + ll] *= f_[e];
        AREL[row * 36 + 16 + ll] *= f_[e];
        if (ll == 0) AREL[row * 36 + 32] *= f_[e];
      }
    }
    // p = exp(s-m); accumulate l, AREL; stage P (bf16, swizzled) in own slab
    float psum[4] = {0.f, 0.f, 0.f, 0.f};
#pragma unroll
    for (int fj = 0; fj < 8; ++fj)
#pragma unroll
      for (int e = 0; e < 4; ++e) {
        float p = __expf(sacc[fj][e] - m_[e]);
        psum[e] += p;
        int iloc = lg * 4 + e;
        atomicAdd(&AREL[(w * 16 + iloc) * 36 + rr_[fj][e]], p);
        *reinterpret_cast<u16*>(PSw + iloc * 256 + (((fj * 16 + ll) * 2) ^ ((iloc & 7) << 4))) = f2b(p);
      }
#pragma unroll
    for (int e = 0; e < 4; ++e) {
      psum[e] += __shfl_xor(psum[e], 1, 64);
      psum[e] += __shfl_xor(psum[e], 2, 64);
      psum[e] += __shfl_xor(psum[e], 4, 64);
      psum[e] += __shfl_xor(psum[e], 8, 64);
      ls_[e] += psum[e];
    }
    __syncthreads();            // all waves' K reads done
    { // stage V(kt): rows d=feature (from vt [d][tok]), cols j, swizzled
      int d = t >> 1, half = t & 1;
      const u16* src = vt + (size_t)(hh * DHD + d) * TOK + b * SLEN + kt * 128;
#pragma unroll
      for (int u = 0; u < 8; ++u) {
        int c = half * 8 + u;
        *reinterpret_cast<uint4*>(KV + d * 256 + ((c * 16) ^ ((d & 7) << 4))) =
            *reinterpret_cast<const uint4*>(src + c * 8);
      }
    }
    __syncthreads();
    // PV: oacc[16 rows][128 d] += P V
#pragma unroll
    for (int kc = 0; kc < 4; ++kc) {
      bf16x8 pa = *reinterpret_cast<const bf16x8*>(PSw + ll * 256 + (((kc * 4 + lg) * 16) ^ ((ll & 7) << 4)));
#pragma unroll
      for (int fd = 0; fd < 8; ++fd) {
        int row = fd * 16 + ll;
        bf16x8 vb = *reinterpret_cast<const bf16x8*>(KV + row * 256 + (((kc * 4 + lg) * 16) ^ ((row & 7) << 4)));
        oacc[fd] = __builtin_amdgcn_mfma_f32_16x16x32_bf16(pa, vb, oacc[fd], 0, 0, 0);
      }
    }
  }
  // ---- epilogue ----
#pragma unroll
  for (int e = 0; e < 4; ++e) {
    float inv = 1.0f / ls_[e];
#pragma unroll
    for (int fd = 0; fd < 8; ++fd) oacc[fd][e] *= inv;
  }
  if (ll == 0)
#pragma unroll
    for (int e = 0; e < 4; ++e) LSUM[w * 16 + lg * 4 + e] = ls_[e];
  __syncthreads();              // PV reads of KV done everywhere
  // stage relv^T bf16 [128 d][64 r] swizzled (zero pad r>=33) into KV
  for (int idx = t; idx < 128 * 64; idx += 256) {
    int d = idx >> 6, r = idx & 63;
    u16 v = (r < RNUM) ? f2b(relv[r * DHD + d]) : (u16)0;
    *reinterpret_cast<u16*>(KV + d * 128 + ((r * 2) ^ ((d & 7) << 4))) = v;
  }
  // arelB = AREL/l bf16 [16][64] into own slab (row stride 128B)
  for (int idx = l; idx < 1024; idx += 64) {
    int ri = idx >> 6, r = idx & 63;
    int row = w * 16 + ri;
    float v = (r < RNUM) ? AREL[row * 36 + r] * (1.0f / LSUM[row]) : 0.f;
    *reinterpret_cast<u16*>(PSw + ri * 128 + ((r * 2) ^ ((ri & 7) << 4))) = f2b(v);
  }
  __syncthreads();              // relvT ready
  // oacc += (arel/l) @ relv
#pragma unroll
  for (int kc = 0; kc < 2; ++kc) {
    bf16x8 pa = *reinterpret_cast<const bf16x8*>(PSw + ll * 128 + (((kc * 4 + lg) * 16) ^ ((ll & 7) << 4)));
#pragma unroll
    for (int fd = 0; fd < 8; ++fd) {
      int row = fd * 16 + ll;
      bf16x8 vb = *reinterpret_cast<const bf16x8*>(KV + row * 128 + (((kc * 4 + lg) * 16) ^ ((row & 7) << 4)));
      oacc[fd] = __builtin_amdgcn_mfma_f32_16x16x32_bf16(pa, vb, oacc[fd], 0, 0, 0);
    }
  }
  // out-stage [16][128] linear in own slab, then coalesced global store
#pragma unroll
  for (int fd = 0; fd < 8; ++fd)
#pragma unroll
    for (int e = 0; e < 4; ++e)
      *reinterpret_cast<u16*>(PSw + ((lg * 4 + e) * 128 + fd * 16 + ll) * 2) = f2b(oacc[fd][e]);
  __syncthreads();
  {
    int ri = l >> 2, q4 = l & 3;
    const char* srcb = PSw + ri * 256 + q4 * 64;
    u16* dst = outb + (size_t)(b * SLEN + i0 + w * 16 + ri) * EDIM + hh * DHD + q4 * 32;
    uint4 x0 = *reinterpret_cast<const uint4*>(srcb);
    uint4 x1 = *reinterpret_cast<const uint4*>(srcb + 16);
    uint4 x2 = *reinterpret_cast<const uint4*>(srcb + 32);
    uint4 x3 = *reinterpret_cast<const uint4*>(srcb + 48);
    *reinterpret_cast<uint4*>(dst)      = x0;
    *reinterpret_cast<uint4*>(dst + 8)  = x1;
    *reinterpret_cast<uint4*>(dst + 16) = x2;
    *reinterpret_cast<uint4*>(dst + 24) = x3;
  }
}

// ---------------- host ----------------
extern "C" void kernel_launch(void* const* d_in, const int* in_sizes, int n_in,
                              void* d_out, int out_size, void* d_ws, size_t ws_size,
                              hipStream_t stream) {
  const float* enc  = (const float*)d_in[0];
  const int*   rel  = (const int*)d_in[1];
  const int*   lens = (const int*)d_in[2];
  const float* Wq = (const float*)d_in[3];
  const float* bq = (const float*)d_in[4];
  const float* Wk = (const float*)d_in[5];
  const float* bk = (const float*)d_in[6];
  const float* Wv = (const float*)d_in[7];
  const float* bv = (const float*)d_in[8];
  const float* Wo = (const float*)d_in[9];
  const float* bo = (const float*)d_in[10];
  const float* relk = (const float*)d_in[11];
  const float* relv = (const float*)d_in[12];
  const float* W1 = (const float*)d_in[13];
  const float* b1 = (const float*)d_in[14];
  const float* W2 = (const float*)d_in[15];
  const float* b2 = (const float*)d_in[16];
  const float* ln1g = (const float*)d_in[17];
  const float* ln1b = (const float*)d_in[18];
  const float* ln2g = (const float*)d_in[19];
  const float* ln2b = (const float*)d_in[20];
  const float* lnfg = (const float*)d_in[21];
  const float* lnfb = (const float*)d_in[22];
  float* out = (float*)d_out;

  char* W = (char*)d_ws;
  u16* h     = (u16*)W;                                // 8 MB
  char* U    = W + 8388608;
  u16* qkb   = (u16*)U;                                // 16 MB  [4096][2048]
  u16* vtb   = (u16*)(U + 16777216);                   // 8 MB   [1024][4096]
  u16* attno = (u16*)(U + 25165824);                   // 8 MB   [4096][1024]
  u16* mid   = (u16*)U;                                // 32 MB  [4096][4096] (aliases qkb/vtb/attno)
  bool xin = ws_size >= (size_t)83886080;
  float* x = xin ? (float*)(W + 41943040) : out;
  char* WT = W + (xin ? 58720256 : 41943040);
  bool big = ws_size >= (size_t)209715200;

  const size_t EE = (size_t)EDIM * EDIM;      // 1M
  const size_t EF = (size_t)EDIM * FFD;       // 4M

  u16 *WqkT, *WvT, *WoT, *W1T, *W2T;
  dim3 blk(256);
  if (big) {
    u16* wqk_all = (u16*)WT;
    u16* wv_all  = wqk_all + 6 * 2 * EE;
    u16* wo_all  = wv_all + 6 * EE;
    u16* w1_all  = wo_all + 6 * EE;
    u16* w2_all  = w1_all + 6 * EF;
    wtrans<<<dim3(32, 32, 6), blk, 0, stream>>>(Wq, wqk_all, 1024, 1024, EE, 2 * EE);
    wtrans<<<dim3(32, 32, 6), blk, 0, stream>>>(Wk, wqk_all + EE, 1024, 1024, EE, 2 * EE);
    wtrans<<<dim3(32, 32, 6), blk, 0, stream>>>(Wv, wv_all, 1024, 1024, EE, EE);
    wtrans<<<dim3(32, 32, 6), blk, 0, stream>>>(Wo, wo_all, 1024, 1024, EE, EE);
    wtrans<<<dim3(128, 32, 6), blk, 0, stream>>>(W1, w1_all, 1024, 4096, EF, EF);
    wtrans<<<dim3(32, 128, 6), blk, 0, stream>>>(W2, w2_all, 4096, 1024, EF, EF);
    WqkT = wqk_all; WvT = wv_all; WoT = wo_all; W1T = w1_all; W2T = w2_all;
  } else {
    WqkT = (u16*)WT;
    WvT  = WqkT + 2 * EE;
    WoT  = WvT + EE;
    W1T  = WoT + EE;
    W2T  = W1T + EF;
  }

  dim3 gLN(TOK);
  for (int ll = 0; ll < LNUM; ++ll) {
    u16 *wqkT, *wvT, *woT, *w1T, *w2T;
    if (big) {
      wqkT = WqkT + (size_t)ll * 2 * EE; wvT = WvT + (size_t)ll * EE; woT = WoT + (size_t)ll * EE;
      w1T = W1T + (size_t)ll * EF; w2T = W2T + (size_t)ll * EF;
    } else {
      wqkT = WqkT; wvT = WvT; woT = WoT; w1T = W1T; w2T = W2T;
      wtrans<<<dim3(32, 32, 1), blk, 0, stream>>>(Wq + ll * EE, wqkT, 1024, 1024, 0, 0);
      wtrans<<<dim3(32, 32, 1), blk, 0, stream>>>(Wk + ll * EE, wqkT + EE, 1024, 1024, 0, 0);
      wtrans<<<dim3(32, 32, 1), blk, 0, stream>>>(Wv + ll * EE, wvT, 1024, 1024, 0, 0);
      wtrans<<<dim3(32, 32, 1), blk, 0, stream>>>(Wo + ll * EE, woT, 1024, 1024, 0, 0);
      wtrans<<<dim3(128, 32, 1), blk, 0, stream>>>(W1 + ll * EF, w1T, 1024, 4096, 0, 0);
      wtrans<<<dim3(32, 128, 1), blk, 0, stream>>>(W2 + ll * EF, w2T, 4096, 1024, 0, 0);
    }
    const float* xin_p = (ll == 0) ? enc : x;
    ln_kernel<1><<<gLN, blk, 0, stream>>>(xin_p, ln1g + ll * EDIM, ln1b + ll * EDIM, h);
    gemm_bt<2, 0, 0, 1><<<dim3(16, 32), blk, 0, stream>>>(h, wqkT, bq + ll * EDIM, bk + ll * EDIM,
                                                          nullptr, qkb, TOK, 2048, EDIM);
    gemm_bt<1, 0, 0, 1><<<dim3(32, 8), blk, 0, stream>>>(wvT, h, bv + ll * EDIM, nullptr,
                                                         nullptr, vtb, EDIM, TOK, EDIM);
    attn_kernel<<<dim3(512), blk, 0, stream>>>(qkb, vtb, rel, lens,
                                               relk + (size_t)ll * RNUM * DHD,
                                               relv + (size_t)ll * RNUM * DHD, attno);
    gemm_bt<0, 0, 1, 0><<<dim3(8, 32), blk, 0, stream>>>(attno, woT, bo + ll * EDIM, nullptr,
                                                         xin_p, x, TOK, EDIM, EDIM);
    ln_kernel<1><<<gLN, blk, 0, stream>>>(x, ln2g + ll * EDIM, ln2b + ll * EDIM, h);
    gemm_bt<0, 1, 0, 1><<<dim3(32, 32), blk, 0, stream>>>(h, w1T, b1 + ll * FFD, nullptr,
                                                          nullptr, mid, TOK, FFD, EDIM);
    gemm_bt<0, 0, 1, 0><<<dim3(8, 32), blk, 0, stream>>>(mid, w2T, b2 + ll * EDIM, nullptr,
                                                         x, x, TOK, EDIM, FFD);
  }
  ln_kernel<0><<<gLN, blk, 0, stream>>>(x, lnfg, lnfb, out);
}

// Round 7
// 2649.765 us; speedup vs baseline: 1.0401x; 1.0401x over previous
//
#include <hip/hip_runtime.h>

#define LNUM 6
#define EDIM 1024
#define HNUM 8
#define DHD  128
#define RNUM 33
#define FFD  4096
#define BNUM 8
#define SLEN 512
#define TOK  (BNUM*SLEN)   // 4096

typedef __attribute__((ext_vector_type(8))) short bf16x8;
typedef __attribute__((ext_vector_type(4))) float f32x4;
typedef unsigned short u16;
typedef unsigned int u32;

__device__ __forceinline__ u16 f2b(float f) {
  u32 u = __builtin_bit_cast(u32, f);
  u32 r = u + 0x7FFFu + ((u >> 16) & 1u);
  return (u16)(r >> 16);
}
__device__ __forceinline__ u32 pck(float a, float b) { return (u32)f2b(a) | ((u32)f2b(b) << 16); }

// async global->LDS, 16B per lane. LDS dest is wave-uniform base + lane*16.
#define GL16(gp, lp) __builtin_amdgcn_global_load_lds(                        \
    (const __attribute__((address_space(1))) void*)(gp),                      \
    (__attribute__((address_space(3))) void*)(lp), 16, 0, 0)

// ---------------- LayerNorm ----------------
template<int BF16OUT>
__global__ __launch_bounds__(256) void ln_kernel(const float* __restrict__ x,
                                                 const float* __restrict__ g,
                                                 const float* __restrict__ be,
                                                 void* __restrict__ o) {
  int row = blockIdx.x;
  int t = threadIdx.x;
  const float* xr = x + (size_t)row * EDIM;
  float4 xv = *reinterpret_cast<const float4*>(xr + t * 4);
  float s1 = xv.x + xv.y + xv.z + xv.w;
  float s2 = xv.x*xv.x + xv.y*xv.y + xv.z*xv.z + xv.w*xv.w;
#pragma unroll
  for (int off = 32; off >= 1; off >>= 1) {
    s1 += __shfl_down(s1, off, 64);
    s2 += __shfl_down(s2, off, 64);
  }
  __shared__ float r1[4], r2[4];
  if ((t & 63) == 0) { r1[t >> 6] = s1; r2[t >> 6] = s2; }
  __syncthreads();
  s1 = r1[0] + r1[1] + r1[2] + r1[3];
  s2 = r2[0] + r2[1] + r2[2] + r2[3];
  float mean = s1 * (1.0f / EDIM);
  float var  = s2 * (1.0f / EDIM) - mean * mean;
  float rstd = rsqrtf(var + 1e-5f);
  float4 gv = *reinterpret_cast<const float4*>(g + t * 4);
  float4 bv = *reinterpret_cast<const float4*>(be + t * 4);
  float o0 = (xv.x - mean) * rstd * gv.x + bv.x;
  float o1 = (xv.y - mean) * rstd * gv.y + bv.y;
  float o2 = (xv.z - mean) * rstd * gv.z + bv.z;
  float o3 = (xv.w - mean) * rstd * gv.w + bv.w;
  if (BF16OUT) {
    ushort4 ov; ov.x = f2b(o0); ov.y = f2b(o1); ov.z = f2b(o2); ov.w = f2b(o3);
    *reinterpret_cast<ushort4*>((u16*)o + (size_t)row * EDIM + t * 4) = ov;
  } else {
    *reinterpret_cast<float4*>((float*)o + (size_t)row * EDIM + t * 4) = make_float4(o0, o1, o2, o3);
  }
}

// ---------------- Weight transpose: f32 [Kd][Nd] -> bf16 [Nd][Kd] ----------------
__global__ __launch_bounds__(256) void wtrans(const float* __restrict__ src0,
                                              u16* __restrict__ dst0,
                                              int Kd, int Nd, size_t sstride, size_t dstride) {
  __shared__ float Ts[32][33];
  const float* src = src0 + blockIdx.z * sstride;
  u16* dst = dst0 + blockIdx.z * dstride;
  int r0 = blockIdx.y * 32, c0 = blockIdx.x * 32;
  int ty = threadIdx.x >> 3, tx = threadIdx.x & 7;
  float4 v = *reinterpret_cast<const float4*>(src + (size_t)(r0 + ty) * Nd + c0 + tx * 4);
  Ts[ty][tx*4+0] = v.x; Ts[ty][tx*4+1] = v.y; Ts[ty][tx*4+2] = v.z; Ts[ty][tx*4+3] = v.w;
  __syncthreads();
  ushort4 o;
  o.x = f2b(Ts[tx*4+0][ty]); o.y = f2b(Ts[tx*4+1][ty]);
  o.z = f2b(Ts[tx*4+2][ty]); o.w = f2b(Ts[tx*4+3][ty]);
  *reinterpret_cast<ushort4*>(dst + (size_t)(c0 + ty) * Kd + r0 + tx * 4) = o;
}

// ---------------- rel pack+transpose: int32 [b][i][j] -> u8 [b][j][i] ----------------
__global__ __launch_bounds__(256) void relpack(const int* __restrict__ rel,
                                               unsigned char* __restrict__ out) {
  __shared__ int Ts[32][33];
  int bz = blockIdx.z;
  int r0 = blockIdx.y * 32, c0 = blockIdx.x * 32;
  int ty = threadIdx.x >> 3, tx = threadIdx.x & 7;
  const int* src = rel + (size_t)bz * SLEN * SLEN;
  int4 v = *reinterpret_cast<const int4*>(src + (size_t)(r0 + ty) * SLEN + c0 + tx * 4);
  Ts[ty][tx*4+0] = v.x; Ts[ty][tx*4+1] = v.y; Ts[ty][tx*4+2] = v.z; Ts[ty][tx*4+3] = v.w;
  __syncthreads();
  u32 o = (u32)(Ts[tx*4+0][ty] & 255) | ((u32)(Ts[tx*4+1][ty] & 255) << 8) |
          ((u32)(Ts[tx*4+2][ty] & 255) << 16) | ((u32)(Ts[tx*4+3][ty] & 255) << 24);
  *reinterpret_cast<u32*>(out + (size_t)bz * SLEN * SLEN + (size_t)(c0 + ty) * SLEN + r0 + tx * 4) = o;
}

// ---------------- bf16 MFMA GEMM: C[M,N] = A[M,K] @ B[N,K]^T ----------------
template<int BIASMODE, int ACT, int RES, int OUTBF16>
__global__ __launch_bounds__(256) void gemm_bt(const u16* __restrict__ A,
                                               const u16* __restrict__ B,
                                               const float* __restrict__ bias0,
                                               const float* __restrict__ bias1,
                                               const float* __restrict__ res,
                                               void* __restrict__ Cv,
                                               int M, int N, int K) {
  __shared__ u16 As[128 * 64];
  __shared__ u16 Bs[128 * 64];
  int t = threadIdx.x;
  int l = t & 63, w = t >> 6;
  int wm = w & 1, wn = w >> 1;
  int m0 = blockIdx.y * 128, n0 = blockIdx.x * 128;
  f32x4 acc[4][4] = {};
  const u16* Agp = A + (size_t)(m0 + w * 32 + (l >> 3)) * K + (l & 7) * 8;
  const u16* Bgp = B + (size_t)(n0 + w * 32 + (l >> 3)) * K + (l & 7) * 8;
  u16* Alp = As + w * 4 * 512;
  u16* Blp = Bs + w * 4 * 512;
  for (int k0 = 0; k0 < K; k0 += 64) {
    __syncthreads();
#pragma unroll
    for (int u = 0; u < 4; ++u) {
      GL16(Agp + (size_t)(u * 8) * K + k0, Alp + u * 512);
      GL16(Bgp + (size_t)(u * 8) * K + k0, Blp + u * 512);
    }
    __syncthreads();
#pragma unroll
    for (int d4 = 0; d4 < 2; ++d4) {
      bf16x8 af[4];
#pragma unroll
      for (int fm = 0; fm < 4; ++fm) {
        int row = wm * 64 + fm * 16 + (l & 15);
        af[fm] = *reinterpret_cast<const bf16x8*>(As + row * 64 + (d4 * 4 + (l >> 4)) * 8);
      }
#pragma unroll
      for (int fn = 0; fn < 4; ++fn) {
        int row = wn * 64 + fn * 16 + (l & 15);
        bf16x8 bf = *reinterpret_cast<const bf16x8*>(Bs + row * 64 + (d4 * 4 + (l >> 4)) * 8);
#pragma unroll
        for (int fm = 0; fm < 4; ++fm)
          acc[fm][fn] = __builtin_amdgcn_mfma_f32_16x16x32_bf16(af[fm], bf, acc[fm][fn], 0, 0, 0);
      }
    }
  }
#pragma unroll
  for (int fm = 0; fm < 4; ++fm)
#pragma unroll
    for (int fn = 0; fn < 4; ++fn)
#pragma unroll
      for (int e = 0; e < 4; ++e) {
        int m = m0 + wm * 64 + fm * 16 + (l >> 4) * 4 + e;
        int n = n0 + wn * 64 + fn * 16 + (l & 15);
        float v = acc[fm][fn][e];
        if (BIASMODE == 0) v += bias0[n];
        if (BIASMODE == 1) v += bias0[m];
        if (BIASMODE == 2) v += (n < 1024) ? bias0[n] : bias1[n - 1024];
        if (ACT == 1) v = fmaxf(v, 0.f);
        if (RES == 1) v += res[(size_t)m * N + n];
        if (OUTBF16) ((u16*)Cv)[(size_t)m * N + n] = f2b(v);
        else ((float*)Cv)[(size_t)m * N + n] = v;
      }
}

// ---------------- Relational attention (flash, latency-pipelined) ----------------
// Block = (b, h, 64 q-rows); wave w owns q-rows [w*16, w*16+16). 4 KV tiles of 128.
// rel8: u8 [b][j][i]  (4 row-values per u32 load). K/V reg-staged, ds_write after
// barrier (T14). All global loads issued >= 1 phase before use.
#define A_KV 0        // 32768: relk[48][128] -> K/V [128][128] swz -> relvT [128][64]
#define A_PS 32768    // 16384: per-wave 4096B slabs: P[16][128] swz / arelB / out-stage
#define A_QR 49152    // 9216: qr f32 [64][36]
#define A_AR 58368    // 9216: AREL f32 [64][36] (wave-private rows)
#define A_LS 67584    // 256 : LSUM f32 [64]
#define A_SM 67840

__global__ __launch_bounds__(256) void attn_kernel(const u16* __restrict__ qk,
                                                   const u16* __restrict__ vt,
                                                   const unsigned char* __restrict__ rel8,
                                                   const int* __restrict__ lens,
                                                   const float* __restrict__ relk,
                                                   const float* __restrict__ relv,
                                                   u16* __restrict__ outb) {
  __align__(16) __shared__ char sm[A_SM];
  char*  KV  = sm + A_KV;
  char*  PSb = sm + A_PS;
  float* QR  = (float*)(sm + A_QR);
  float* AREL = (float*)(sm + A_AR);
  float* LSUM = (float*)(sm + A_LS);

  const int t = threadIdx.x;
  const int l = t & 63, w = t >> 6;
  const int lg = l >> 4;        // 0..3
  const int ll = l & 15;        // 0..15
  // XCD-aware mapping: all 8 q-tiles (it) of one (b,hh) share an XCD -> K/V L2 hits
  const int bx = blockIdx.x;
  const int xcd = bx & 7, rem = bx >> 3, slot = rem & 7, it = rem >> 3;
  const int g = slot * 8 + xcd;
  const int b = g >> 3, hh = g & 7;
  const int i0 = it * 64;
  const int len = lens[b];
  const float scale = 0.08838834764831845f;
  char* PSw = PSb + w * 4096;

  // ---- prologue: issue K(0) and rel(0) immediately (latency hides under relk/QR) ----
  uint4 kreg[8];
  u32 relw[8];
  const int jrow = t >> 1, jhalf = t & 1;
  {
    const u16* src = qk + (size_t)(b * SLEN + jrow) * 2048 + 1024 + hh * DHD;
#pragma unroll
    for (int u = 0; u < 8; ++u)
      kreg[u] = *reinterpret_cast<const uint4*>(src + (jhalf * 8 + u) * 8);
  }
  const unsigned char* relbase = rel8 + (size_t)b * SLEN * SLEN + (i0 + w * 16 + lg * 4);
  {
    const unsigned char* rb = relbase + (size_t)ll * SLEN;
#pragma unroll
    for (int fj = 0; fj < 8; ++fj)
      relw[fj] = *reinterpret_cast<const u32*>(rb + (size_t)(fj * 16) * SLEN);
  }
  // zero own AREL rows
  for (int idx = l; idx < 16 * 36; idx += 64) AREL[w * 16 * 36 + idx] = 0.f;
  // stage relk bf16 [48][128] swizzled into KV
  if (t < 192) {
    int r = t >> 2, sub = t & 3;
#pragma unroll
    for (int u = 0; u < 4; ++u) {
      int seg = sub * 4 + u;
      uint4 o;
      if (r < RNUM) {
        float4 f0 = *reinterpret_cast<const float4*>(relk + r * DHD + seg * 8);
        float4 f1 = *reinterpret_cast<const float4*>(relk + r * DHD + seg * 8 + 4);
        o.x = pck(f0.x, f0.y); o.y = pck(f0.z, f0.w);
        o.z = pck(f1.x, f1.y); o.w = pck(f1.z, f1.w);
      } else { o.x = o.y = o.z = o.w = 0u; }
      *reinterpret_cast<uint4*>(KV + r * 256 + ((seg * 16) ^ ((r & 7) << 4))) = o;
    }
  }
  // Q fragments (global -> reg)
  bf16x8 aq[4];
  {
    const u16* qrow = qk + (size_t)(b * SLEN + i0 + w * 16 + ll) * 2048 + hh * DHD;
#pragma unroll
    for (int d4 = 0; d4 < 4; ++d4)
      aq[d4] = *reinterpret_cast<const bf16x8*>(qrow + (d4 * 4 + lg) * 8);
  }
  __syncthreads();   // relk staged
  // qr = Q @ relk^T -> QR (own-wave rows)
#pragma unroll
  for (int rb = 0; rb < 3; ++rb) {
    f32x4 acc = {};
#pragma unroll
    for (int d4 = 0; d4 < 4; ++d4) {
      int rr = rb * 16 + ll;
      bf16x8 br = *reinterpret_cast<const bf16x8*>(KV + rr * 256 + (((d4 * 4 + lg) * 16) ^ ((rr & 7) << 4)));
      acc = __builtin_amdgcn_mfma_f32_16x16x32_bf16(aq[d4], br, acc, 0, 0, 0);
    }
    int col = rb * 16 + ll;
    if (col < 36)
#pragma unroll
      for (int e = 0; e < 4; ++e)
        QR[(w * 16 + lg * 4 + e) * 36 + col] = acc[e];
  }
  __syncthreads();   // all relk reads done
  { // write K(0) from regs (data long since arrived)
#pragma unroll
    for (int u = 0; u < 8; ++u) {
      int c = jhalf * 8 + u;
      *reinterpret_cast<uint4*>(KV + jrow * 256 + ((c * 16) ^ ((jrow & 7) << 4))) = kreg[u];
    }
  }
  __syncthreads();   // K(0) ready

  bool rowv[4];
#pragma unroll
  for (int e = 0; e < 4; ++e) rowv[e] = (i0 + w * 16 + lg * 4 + e) < len;

  float m_[4], ls_[4];
#pragma unroll
  for (int e = 0; e < 4; ++e) { m_[e] = -3.0e38f; ls_[e] = 0.f; }
  f32x4 oacc[8] = {};

  for (int kt = 0; kt < 4; ++kt) {
    // issue V(kt) -> regs (hidden under QK + softmax)
    uint4 vreg[8];
    {
      const u16* src = vt + (size_t)(hh * DHD + jrow) * TOK + b * SLEN + kt * 128;
#pragma unroll
      for (int u = 0; u < 8; ++u)
        vreg[u] = *reinterpret_cast<const uint4*>(src + (jhalf * 8 + u) * 8);
    }
    // QK^T
    __builtin_amdgcn_s_setprio(1);
    f32x4 sacc[8];
#pragma unroll
    for (int fj = 0; fj < 8; ++fj) {
      f32x4 a = {};
#pragma unroll
      for (int d4 = 0; d4 < 4; ++d4) {
        int row = fj * 16 + ll;
        bf16x8 bk_ = *reinterpret_cast<const bf16x8*>(KV + row * 256 + (((d4 * 4 + lg) * 16) ^ ((row & 7) << 4)));
        a = __builtin_amdgcn_mfma_f32_16x16x32_bf16(aq[d4], bk_, a, 0, 0, 0);
      }
      sacc[fj] = a;
    }
    __builtin_amdgcn_s_setprio(0);
    // fixup: + qr[rel] (rel from prefetched regs), scale, mask; tile max
    float pmax[4] = {-3.0e38f, -3.0e38f, -3.0e38f, -3.0e38f};
    int rr_[8][4];
#pragma unroll
    for (int fj = 0; fj < 8; ++fj) {
      bool colv = (kt * 128 + fj * 16 + ll) < len;
      u32 rw = relw[fj];
#pragma unroll
      for (int e = 0; e < 4; ++e) {
        int r = (rw >> (8 * e)) & 255;
        rr_[fj][e] = r;
        float s = (sacc[fj][e] + QR[(w * 16 + lg * 4 + e) * 36 + r]) * scale;
        s = (rowv[e] && colv) ? s : -1e9f;
        sacc[fj][e] = s;
        pmax[e] = fmaxf(pmax[e], s);
      }
    }
#pragma unroll
    for (int e = 0; e < 4; ++e) {
      pmax[e] = fmaxf(pmax[e], __shfl_xor(pmax[e], 1, 64));
      pmax[e] = fmaxf(pmax[e], __shfl_xor(pmax[e], 2, 64));
      pmax[e] = fmaxf(pmax[e], __shfl_xor(pmax[e], 4, 64));
      pmax[e] = fmaxf(pmax[e], __shfl_xor(pmax[e], 8, 64));
    }
    float f_[4];
#pragma unroll
    for (int e = 0; e < 4; ++e) {
      float mn = fmaxf(m_[e], pmax[e]);
      f_[e] = __expf(m_[e] - mn);
      m_[e] = mn;
      ls_[e] *= f_[e];
    }
#pragma unroll
    for (int fd = 0; fd < 8; ++fd)
#pragma unroll
      for (int e = 0; e < 4; ++e) oacc[fd][e] *= f_[e];
#pragma unroll
    for (int e = 0; e < 4; ++e) {
      if (f_[e] != 1.0f) {
        int row = w * 16 + lg * 4 + e;
        AREL[row * 36 + ll] *= f_[e];
        AREL[row * 36 + 16 + ll] *= f_[e];
        if (ll == 0) AREL[row * 36 + 32] *= f_[e];
      }
    }
    float psum[4] = {0.f, 0.f, 0.f, 0.f};
#pragma unroll
    for (int fj = 0; fj < 8; ++fj)
#pragma unroll
      for (int e = 0; e < 4; ++e) {
        float p = __expf(sacc[fj][e] - m_[e]);
        psum[e] += p;
        int iloc = lg * 4 + e;
        atomicAdd(&AREL[(w * 16 + iloc) * 36 + rr_[fj][e]], p);
        *reinterpret_cast<u16*>(PSw + iloc * 256 + (((fj * 16 + ll) * 2) ^ ((iloc & 7) << 4))) = f2b(p);
      }
#pragma unroll
    for (int e = 0; e < 4; ++e) {
      psum[e] += __shfl_xor(psum[e], 1, 64);
      psum[e] += __shfl_xor(psum[e], 2, 64);
      psum[e] += __shfl_xor(psum[e], 4, 64);
      psum[e] += __shfl_xor(psum[e], 8, 64);
      ls_[e] += psum[e];
    }
    // prefetch rel(kt+1)
    if (kt < 3) {
      const unsigned char* rb = relbase + (size_t)((kt + 1) * 128 + ll) * SLEN;
#pragma unroll
      for (int fj = 0; fj < 8; ++fj)
        relw[fj] = *reinterpret_cast<const u32*>(rb + (size_t)(fj * 16) * SLEN);
    }
    __syncthreads();            // all waves done reading K(kt)
    { // write V(kt) from regs
#pragma unroll
      for (int u = 0; u < 8; ++u) {
        int c = jhalf * 8 + u;
        *reinterpret_cast<uint4*>(KV + jrow * 256 + ((c * 16) ^ ((jrow & 7) << 4))) = vreg[u];
      }
    }
    __syncthreads();            // V ready
    // issue K(kt+1) -> regs (hidden under PV)
    if (kt < 3) {
      const u16* src = qk + (size_t)(b * SLEN + (kt + 1) * 128 + jrow) * 2048 + 1024 + hh * DHD;
#pragma unroll
      for (int u = 0; u < 8; ++u)
        kreg[u] = *reinterpret_cast<const uint4*>(src + (jhalf * 8 + u) * 8);
    }
    // PV
    __builtin_amdgcn_s_setprio(1);
#pragma unroll
    for (int kc = 0; kc < 4; ++kc) {
      bf16x8 pa = *reinterpret_cast<const bf16x8*>(PSw + ll * 256 + (((kc * 4 + lg) * 16) ^ ((ll & 7) << 4)));
#pragma unroll
      for (int fd = 0; fd < 8; ++fd) {
        int row = fd * 16 + ll;
        bf16x8 vb = *reinterpret_cast<const bf16x8*>(KV + row * 256 + (((kc * 4 + lg) * 16) ^ ((row & 7) << 4)));
        oacc[fd] = __builtin_amdgcn_mfma_f32_16x16x32_bf16(pa, vb, oacc[fd], 0, 0, 0);
      }
    }
    __builtin_amdgcn_s_setprio(0);
    __syncthreads();            // all waves done reading V(kt)
    if (kt < 3) {
      { // write K(kt+1)
#pragma unroll
        for (int u = 0; u < 8; ++u) {
          int c = jhalf * 8 + u;
          *reinterpret_cast<uint4*>(KV + jrow * 256 + ((c * 16) ^ ((jrow & 7) << 4))) = kreg[u];
        }
      }
      __syncthreads();          // K(kt+1) ready
    }
  }
  // ---- epilogue ----
#pragma unroll
  for (int e = 0; e < 4; ++e) {
    float inv = 1.0f / ls_[e];
#pragma unroll
    for (int fd = 0; fd < 8; ++fd) oacc[fd][e] *= inv;
  }
  if (ll == 0)
#pragma unroll
    for (int e = 0; e < 4; ++e) LSUM[w * 16 + lg * 4 + e] = ls_[e];
  // stage relv^T bf16 [128 d][64 r] swizzled into KV (KV free: V-done barrier passed)
  for (int idx = t; idx < 128 * 64; idx += 256) {
    int d = idx >> 6, r = idx & 63;
    u16 v = (r < RNUM) ? f2b(relv[r * DHD + d]) : (u16)0;
    *reinterpret_cast<u16*>(KV + d * 128 + ((r * 2) ^ ((d & 7) << 4))) = v;
  }
  // arelB = AREL/l bf16 [16][64] into own slab
  for (int idx = l; idx < 1024; idx += 64) {
    int ri = idx >> 6, r = idx & 63;
    int row = w * 16 + ri;
    float v = (r < RNUM) ? AREL[row * 36 + r] * (1.0f / LSUM[row]) : 0.f;
    *reinterpret_cast<u16*>(PSw + ri * 128 + ((r * 2) ^ ((ri & 7) << 4))) = f2b(v);
  }
  __syncthreads();              // relvT ready
#pragma unroll
  for (int kc = 0; kc < 2; ++kc) {
    bf16x8 pa = *reinterpret_cast<const bf16x8*>(PSw + ll * 128 + (((kc * 4 + lg) * 16) ^ ((ll & 7) << 4)));
#pragma unroll
    for (int fd = 0; fd < 8; ++fd) {
      int row = fd * 16 + ll;
      bf16x8 vb = *reinterpret_cast<const bf16x8*>(KV + row * 128 + (((kc * 4 + lg) * 16) ^ ((row & 7) << 4)));
      oacc[fd] = __builtin_amdgcn_mfma_f32_16x16x32_bf16(pa, vb, oacc[fd], 0, 0, 0);
    }
  }
#pragma unroll
  for (int fd = 0; fd < 8; ++fd)
#pragma unroll
    for (int e = 0; e < 4; ++e)
      *reinterpret_cast<u16*>(PSw + ((lg * 4 + e) * 128 + fd * 16 + ll) * 2) = f2b(oacc[fd][e]);
  __syncthreads();
  {
    int ri = l >> 2, q4 = l & 3;
    const char* srcb = PSw + ri * 256 + q4 * 64;
    u16* dst = outb + (size_t)(b * SLEN + i0 + w * 16 + ri) * EDIM + hh * DHD + q4 * 32;
    uint4 x0 = *reinterpret_cast<const uint4*>(srcb);
    uint4 x1 = *reinterpret_cast<const uint4*>(srcb + 16);
    uint4 x2 = *reinterpret_cast<const uint4*>(srcb + 32);
    uint4 x3 = *reinterpret_cast<const uint4*>(srcb + 48);
    *reinterpret_cast<uint4*>(dst)      = x0;
    *reinterpret_cast<uint4*>(dst + 8)  = x1;
    *reinterpret_cast<uint4*>(dst + 16) = x2;
    *reinterpret_cast<uint4*>(dst + 24) = x3;
  }
}

// ---------------- host ----------------
extern "C" void kernel_launch(void* const* d_in, const int* in_sizes, int n_in,
                              void* d_out, int out_size, void* d_ws, size_t ws_size,
                              hipStream_t stream) {
  const float* enc  = (const float*)d_in[0];
  const int*   rel  = (const int*)d_in[1];
  const int*   lens = (const int*)d_in[2];
  const float* Wq = (const float*)d_in[3];
  const float* bq = (const float*)d_in[4];
  const float* Wk = (const float*)d_in[5];
  const float* bk = (const float*)d_in[6];
  const float* Wv = (const float*)d_in[7];
  const float* bv = (const float*)d_in[8];
  const float* Wo = (const float*)d_in[9];
  const float* bo = (const float*)d_in[10];
  const float* relk = (const float*)d_in[11];
  const float* relv = (const float*)d_in[12];
  const float* W1 = (const float*)d_in[13];
  const float* b1 = (const float*)d_in[14];
  const float* W2 = (const float*)d_in[15];
  const float* b2 = (const float*)d_in[16];
  const float* ln1g = (const float*)d_in[17];
  const float* ln1b = (const float*)d_in[18];
  const float* ln2g = (const float*)d_in[19];
  const float* ln2b = (const float*)d_in[20];
  const float* lnfg = (const float*)d_in[21];
  const float* lnfb = (const float*)d_in[22];
  float* out = (float*)d_out;

  char* W = (char*)d_ws;
  u16* h     = (u16*)W;                                // 8 MB (dead during attn -> holds rel8)
  unsigned char* rel8 = (unsigned char*)W;             // 2.1 MB, rebuilt per layer
  char* U    = W + 8388608;
  u16* qkb   = (u16*)U;                                // 16 MB  [4096][2048]
  u16* vtb   = (u16*)(U + 16777216);                   // 8 MB   [1024][4096]
  u16* attno = (u16*)(U + 25165824);                   // 8 MB   [4096][1024]
  u16* mid   = (u16*)U;                                // 32 MB  (aliases qkb/vtb/attno)
  bool xin = ws_size >= (size_t)83886080;
  float* x = xin ? (float*)(W + 41943040) : out;
  char* WT = W + (xin ? 58720256 : 41943040);
  bool big = ws_size >= (size_t)209715200;

  const size_t EE = (size_t)EDIM * EDIM;      // 1M
  const size_t EF = (size_t)EDIM * FFD;       // 4M

  u16 *WqkT, *WvT, *WoT, *W1T, *W2T;
  dim3 blk(256);
  if (big) {
    u16* wqk_all = (u16*)WT;
    u16* wv_all  = wqk_all + 6 * 2 * EE;
    u16* wo_all  = wv_all + 6 * EE;
    u16* w1_all  = wo_all + 6 * EE;
    u16* w2_all  = w1_all + 6 * EF;
    wtrans<<<dim3(32, 32, 6), blk, 0, stream>>>(Wq, wqk_all, 1024, 1024, EE, 2 * EE);
    wtrans<<<dim3(32, 32, 6), blk, 0, stream>>>(Wk, wqk_all + EE, 1024, 1024, EE, 2 * EE);
    wtrans<<<dim3(32, 32, 6), blk, 0, stream>>>(Wv, wv_all, 1024, 1024, EE, EE);
    wtrans<<<dim3(32, 32, 6), blk, 0, stream>>>(Wo, wo_all, 1024, 1024, EE, EE);
    wtrans<<<dim3(128, 32, 6), blk, 0, stream>>>(W1, w1_all, 1024, 4096, EF, EF);
    wtrans<<<dim3(32, 128, 6), blk, 0, stream>>>(W2, w2_all, 4096, 1024, EF, EF);
    WqkT = wqk_all; WvT = wv_all; WoT = wo_all; W1T = w1_all; W2T = w2_all;
  } else {
    WqkT = (u16*)WT;
    WvT  = WqkT + 2 * EE;
    WoT  = WvT + EE;
    W1T  = WoT + EE;
    W2T  = W1T + EF;
  }

  dim3 gLN(TOK);
  for (int ll = 0; ll < LNUM; ++ll) {
    u16 *wqkT, *wvT, *woT, *w1T, *w2T;
    if (big) {
      wqkT = WqkT + (size_t)ll * 2 * EE; wvT = WvT + (size_t)ll * EE; woT = WoT + (size_t)ll * EE;
      w1T = W1T + (size_t)ll * EF; w2T = W2T + (size_t)ll * EF;
    } else {
      wqkT = WqkT; wvT = WvT; woT = WoT; w1T = W1T; w2T = W2T;
      wtrans<<<dim3(32, 32, 1), blk, 0, stream>>>(Wq + ll * EE, wqkT, 1024, 1024, 0, 0);
      wtrans<<<dim3(32, 32, 1), blk, 0, stream>>>(Wk + ll * EE, wqkT + EE, 1024, 1024, 0, 0);
      wtrans<<<dim3(32, 32, 1), blk, 0, stream>>>(Wv + ll * EE, wvT, 1024, 1024, 0, 0);
      wtrans<<<dim3(32, 32, 1), blk, 0, stream>>>(Wo + ll * EE, woT, 1024, 1024, 0, 0);
      wtrans<<<dim3(128, 32, 1), blk, 0, stream>>>(W1 + ll * EF, w1T, 1024, 4096, 0, 0);
      wtrans<<<dim3(32, 128, 1), blk, 0, stream>>>(W2 + ll * EF, w2T, 4096, 1024, 0, 0);
    }
    const float* xin_p = (ll == 0) ? enc : x;
    ln_kernel<1><<<gLN, blk, 0, stream>>>(xin_p, ln1g + ll * EDIM, ln1b + ll * EDIM, h);
    gemm_bt<2, 0, 0, 1><<<dim3(16, 32), blk, 0, stream>>>(h, wqkT, bq + ll * EDIM, bk + ll * EDIM,
                                                          nullptr, qkb, TOK, 2048, EDIM);
    gemm_bt<1, 0, 0, 1><<<dim3(32, 8), blk, 0, stream>>>(wvT, h, bv + ll * EDIM, nullptr,
                                                         nullptr, vtb, EDIM, TOK, EDIM);
    // h is dead now -> rebuild rel8 (u8 transposed) in its place
    relpack<<<dim3(16, 16, 8), blk, 0, stream>>>(rel, rel8);
    attn_kernel<<<dim3(512), blk, 0, stream>>>(qkb, vtb, rel8, lens,
                                               relk + (size_t)ll * RNUM * DHD,
                                               relv + (size_t)ll * RNUM * DHD, attno);
    gemm_bt<0, 0, 1, 0><<<dim3(8, 32), blk, 0, stream>>>(attno, woT, bo + ll * EDIM, nullptr,
                                                         xin_p, x, TOK, EDIM, EDIM);
    ln_kernel<1><<<gLN, blk, 0, stream>>>(x, ln2g + ll * EDIM, ln2b + ll * EDIM, h);
    gemm_bt<0, 1, 0, 1><<<dim3(32, 32), blk, 0, stream>>>(h, w1T, b1 + ll * FFD, nullptr,
                                                          nullptr, mid, TOK, FFD, EDIM);
    gemm_bt<0, 0, 1, 0><<<dim3(8, 32), blk, 0, stream>>>(mid, w2T, b2 + ll * EDIM, nullptr,
                                                         x, x, TOK, EDIM, FFD);
  }
  ln_kernel<0><<<gLN, blk, 0, stream>>>(x, lnfg, lnfb, out);
}

// Round 8
// 2558.289 us; speedup vs baseline: 1.0773x; 1.0358x over previous
//
#include <hip/hip_runtime.h>

#define LNUM 6
#define EDIM 1024
#define HNUM 8
#define DHD  128
#define RNUM 33
#define FFD  4096
#define BNUM 8
#define SLEN 512
#define TOK  (BNUM*SLEN)   // 4096

typedef __attribute__((ext_vector_type(8))) short bf16x8;
typedef __attribute__((ext_vector_type(4))) float f32x4;
typedef unsigned short u16;
typedef unsigned int u32;

__device__ __forceinline__ u16 f2b(float f) {
  u32 u = __builtin_bit_cast(u32, f);
  u32 r = u + 0x7FFFu + ((u >> 16) & 1u);
  return (u16)(r >> 16);
}
__device__ __forceinline__ u32 pck(float a, float b) { return (u32)f2b(a) | ((u32)f2b(b) << 16); }

// async global->LDS, 16B per lane. LDS dest is wave-uniform base + lane*16.
#define GL16(gp, lp) __builtin_amdgcn_global_load_lds(                        \
    (const __attribute__((address_space(1))) void*)(gp),                      \
    (__attribute__((address_space(3))) void*)(lp), 16, 0, 0)

// ---------------- LayerNorm ----------------
template<int BF16OUT>
__global__ __launch_bounds__(256) void ln_kernel(const float* __restrict__ x,
                                                 const float* __restrict__ g,
                                                 const float* __restrict__ be,
                                                 void* __restrict__ o) {
  int row = blockIdx.x;
  int t = threadIdx.x;
  const float* xr = x + (size_t)row * EDIM;
  float4 xv = *reinterpret_cast<const float4*>(xr + t * 4);
  float s1 = xv.x + xv.y + xv.z + xv.w;
  float s2 = xv.x*xv.x + xv.y*xv.y + xv.z*xv.z + xv.w*xv.w;
#pragma unroll
  for (int off = 32; off >= 1; off >>= 1) {
    s1 += __shfl_down(s1, off, 64);
    s2 += __shfl_down(s2, off, 64);
  }
  __shared__ float r1[4], r2[4];
  if ((t & 63) == 0) { r1[t >> 6] = s1; r2[t >> 6] = s2; }
  __syncthreads();
  s1 = r1[0] + r1[1] + r1[2] + r1[3];
  s2 = r2[0] + r2[1] + r2[2] + r2[3];
  float mean = s1 * (1.0f / EDIM);
  float var  = s2 * (1.0f / EDIM) - mean * mean;
  float rstd = rsqrtf(var + 1e-5f);
  float4 gv = *reinterpret_cast<const float4*>(g + t * 4);
  float4 bv = *reinterpret_cast<const float4*>(be + t * 4);
  float o0 = (xv.x - mean) * rstd * gv.x + bv.x;
  float o1 = (xv.y - mean) * rstd * gv.y + bv.y;
  float o2 = (xv.z - mean) * rstd * gv.z + bv.z;
  float o3 = (xv.w - mean) * rstd * gv.w + bv.w;
  if (BF16OUT) {
    ushort4 ov; ov.x = f2b(o0); ov.y = f2b(o1); ov.z = f2b(o2); ov.w = f2b(o3);
    *reinterpret_cast<ushort4*>((u16*)o + (size_t)row * EDIM + t * 4) = ov;
  } else {
    *reinterpret_cast<float4*>((float*)o + (size_t)row * EDIM + t * 4) = make_float4(o0, o1, o2, o3);
  }
}

// ---------------- Weight transpose: f32 [Kd][Nd] -> bf16 [Nd][Kd] ----------------
__global__ __launch_bounds__(256) void wtrans(const float* __restrict__ src0,
                                              u16* __restrict__ dst0,
                                              int Kd, int Nd, size_t sstride, size_t dstride) {
  __shared__ float Ts[32][33];
  const float* src = src0 + blockIdx.z * sstride;
  u16* dst = dst0 + blockIdx.z * dstride;
  int r0 = blockIdx.y * 32, c0 = blockIdx.x * 32;
  int ty = threadIdx.x >> 3, tx = threadIdx.x & 7;
  float4 v = *reinterpret_cast<const float4*>(src + (size_t)(r0 + ty) * Nd + c0 + tx * 4);
  Ts[ty][tx*4+0] = v.x; Ts[ty][tx*4+1] = v.y; Ts[ty][tx*4+2] = v.z; Ts[ty][tx*4+3] = v.w;
  __syncthreads();
  ushort4 o;
  o.x = f2b(Ts[tx*4+0][ty]); o.y = f2b(Ts[tx*4+1][ty]);
  o.z = f2b(Ts[tx*4+2][ty]); o.w = f2b(Ts[tx*4+3][ty]);
  *reinterpret_cast<ushort4*>(dst + (size_t)(c0 + ty) * Kd + r0 + tx * 4) = o;
}

// ---------------- rel pack+transpose: int32 [b][i][j] -> u8 [b][j][i] ----------------
__global__ __launch_bounds__(256) void relpack(const int* __restrict__ rel,
                                               unsigned char* __restrict__ out) {
  __shared__ int Ts[32][33];
  int bz = blockIdx.z;
  int r0 = blockIdx.y * 32, c0 = blockIdx.x * 32;
  int ty = threadIdx.x >> 3, tx = threadIdx.x & 7;
  const int* src = rel + (size_t)bz * SLEN * SLEN;
  int4 v = *reinterpret_cast<const int4*>(src + (size_t)(r0 + ty) * SLEN + c0 + tx * 4);
  Ts[ty][tx*4+0] = v.x; Ts[ty][tx*4+1] = v.y; Ts[ty][tx*4+2] = v.z; Ts[ty][tx*4+3] = v.w;
  __syncthreads();
  u32 o = (u32)(Ts[tx*4+0][ty] & 255) | ((u32)(Ts[tx*4+1][ty] & 255) << 8) |
          ((u32)(Ts[tx*4+2][ty] & 255) << 16) | ((u32)(Ts[tx*4+3][ty] & 255) << 24);
  *reinterpret_cast<u32*>(out + (size_t)bz * SLEN * SLEN + (size_t)(c0 + ty) * SLEN + r0 + tx * 4) = o;
}

// ---------------- bf16 MFMA GEMM: C[M,N] = A[M,K] @ B[N,K]^T ----------------
template<int BIASMODE, int ACT, int RES, int OUTBF16>
__global__ __launch_bounds__(256) void gemm_bt(const u16* __restrict__ A,
                                               const u16* __restrict__ B,
                                               const float* __restrict__ bias0,
                                               const float* __restrict__ bias1,
                                               const float* __restrict__ res,
                                               void* __restrict__ Cv,
                                               int M, int N, int K) {
  __shared__ u16 As[128 * 64];
  __shared__ u16 Bs[128 * 64];
  int t = threadIdx.x;
  int l = t & 63, w = t >> 6;
  int wm = w & 1, wn = w >> 1;
  int m0 = blockIdx.y * 128, n0 = blockIdx.x * 128;
  f32x4 acc[4][4] = {};
  const u16* Agp = A + (size_t)(m0 + w * 32 + (l >> 3)) * K + (l & 7) * 8;
  const u16* Bgp = B + (size_t)(n0 + w * 32 + (l >> 3)) * K + (l & 7) * 8;
  u16* Alp = As + w * 4 * 512;
  u16* Blp = Bs + w * 4 * 512;
  for (int k0 = 0; k0 < K; k0 += 64) {
    __syncthreads();
#pragma unroll
    for (int u = 0; u < 4; ++u) {
      GL16(Agp + (size_t)(u * 8) * K + k0, Alp + u * 512);
      GL16(Bgp + (size_t)(u * 8) * K + k0, Blp + u * 512);
    }
    __syncthreads();
#pragma unroll
    for (int d4 = 0; d4 < 2; ++d4) {
      bf16x8 af[4];
#pragma unroll
      for (int fm = 0; fm < 4; ++fm) {
        int row = wm * 64 + fm * 16 + (l & 15);
        af[fm] = *reinterpret_cast<const bf16x8*>(As + row * 64 + (d4 * 4 + (l >> 4)) * 8);
      }
#pragma unroll
      for (int fn = 0; fn < 4; ++fn) {
        int row = wn * 64 + fn * 16 + (l & 15);
        bf16x8 bf = *reinterpret_cast<const bf16x8*>(Bs + row * 64 + (d4 * 4 + (l >> 4)) * 8);
#pragma unroll
        for (int fm = 0; fm < 4; ++fm)
          acc[fm][fn] = __builtin_amdgcn_mfma_f32_16x16x32_bf16(af[fm], bf, acc[fm][fn], 0, 0, 0);
      }
    }
  }
#pragma unroll
  for (int fm = 0; fm < 4; ++fm)
#pragma unroll
    for (int fn = 0; fn < 4; ++fn)
#pragma unroll
      for (int e = 0; e < 4; ++e) {
        int m = m0 + wm * 64 + fm * 16 + (l >> 4) * 4 + e;
        int n = n0 + wn * 64 + fn * 16 + (l & 15);
        float v = acc[fm][fn][e];
        if (BIASMODE == 0) v += bias0[n];
        if (BIASMODE == 1) v += bias0[m];
        if (BIASMODE == 2) v += (n < 1024) ? bias0[n] : bias1[n - 1024];
        if (ACT == 1) v = fmaxf(v, 0.f);
        if (RES == 1) v += res[(size_t)m * N + n];
        if (OUTBF16) ((u16*)Cv)[(size_t)m * N + n] = f2b(v);
        else ((float*)Cv)[(size_t)m * N + n] = v;
      }
}

// ---------------- Relational attention (flash, latency-pipelined) ----------------
// Block = (b, h, 64 q-rows); wave w owns q-rows [w*16, w*16+16). 4 KV tiles of 128.
// __launch_bounds__(256, 2): 2 waves/SIMD -> VGPR cap 256, no scratch spills
// (R7 at 136 VGPRs spilled ~100 MB/dispatch to scratch -> WRITE_SIZE 112 MB).
#define A_KV 0        // 32768: relk[48][128] -> K/V [128][128] swz -> relvT [128][64]
#define A_PS 32768    // 16384: per-wave 4096B slabs: P[16][128] swz / arelB / out-stage
#define A_QR 49152    // 9216: qr f32 [64][36]
#define A_AR 58368    // 9216: AREL f32 [64][36] (wave-private rows)
#define A_LS 67584    // 256 : LSUM f32 [64]
#define A_SM 67840

__global__ __launch_bounds__(256, 2) void attn_kernel(const u16* __restrict__ qk,
                                                      const u16* __restrict__ vt,
                                                      const unsigned char* __restrict__ rel8,
                                                      const int* __restrict__ lens,
                                                      const float* __restrict__ relk,
                                                      const float* __restrict__ relv,
                                                      u16* __restrict__ outb) {
  __align__(16) __shared__ char sm[A_SM];
  char*  KV  = sm + A_KV;
  char*  PSb = sm + A_PS;
  float* QR  = (float*)(sm + A_QR);
  float* AREL = (float*)(sm + A_AR);
  float* LSUM = (float*)(sm + A_LS);

  const int t = threadIdx.x;
  const int l = t & 63, w = t >> 6;
  const int lg = l >> 4;        // 0..3
  const int ll = l & 15;        // 0..15
  // XCD-aware mapping: all 8 q-tiles (it) of one (b,hh) share an XCD -> K/V L2 hits
  const int bx = blockIdx.x;
  const int xcd = bx & 7, rem = bx >> 3, slot = rem & 7, it = rem >> 3;
  const int g = slot * 8 + xcd;
  const int b = g >> 3, hh = g & 7;
  const int i0 = it * 64;
  const int len = lens[b];
  const float scale = 0.08838834764831845f;
  char* PSw = PSb + w * 4096;

  // ---- prologue: issue K(0) and rel(0) immediately ----
  uint4 kreg[8];
  u32 relw[8];
  const int jrow = t >> 1, jhalf = t & 1;
  {
    const u16* src = qk + (size_t)(b * SLEN + jrow) * 2048 + 1024 + hh * DHD;
#pragma unroll
    for (int u = 0; u < 8; ++u)
      kreg[u] = *reinterpret_cast<const uint4*>(src + (jhalf * 8 + u) * 8);
  }
  const unsigned char* relbase = rel8 + (size_t)b * SLEN * SLEN + (i0 + w * 16 + lg * 4);
  {
    const unsigned char* rb = relbase + (size_t)ll * SLEN;
#pragma unroll
    for (int fj = 0; fj < 8; ++fj)
      relw[fj] = *reinterpret_cast<const u32*>(rb + (size_t)(fj * 16) * SLEN);
  }
  // zero own AREL rows
  for (int idx = l; idx < 16 * 36; idx += 64) AREL[w * 16 * 36 + idx] = 0.f;
  // stage relk bf16 [48][128] swizzled into KV
  if (t < 192) {
    int r = t >> 2, sub = t & 3;
#pragma unroll
    for (int u = 0; u < 4; ++u) {
      int seg = sub * 4 + u;
      uint4 o;
      if (r < RNUM) {
        float4 f0 = *reinterpret_cast<const float4*>(relk + r * DHD + seg * 8);
        float4 f1 = *reinterpret_cast<const float4*>(relk + r * DHD + seg * 8 + 4);
        o.x = pck(f0.x, f0.y); o.y = pck(f0.z, f0.w);
        o.z = pck(f1.x, f1.y); o.w = pck(f1.z, f1.w);
      } else { o.x = o.y = o.z = o.w = 0u; }
      *reinterpret_cast<uint4*>(KV + r * 256 + ((seg * 16) ^ ((r & 7) << 4))) = o;
    }
  }
  // Q fragments (global -> reg)
  bf16x8 aq[4];
  {
    const u16* qrow = qk + (size_t)(b * SLEN + i0 + w * 16 + ll) * 2048 + hh * DHD;
#pragma unroll
    for (int d4 = 0; d4 < 4; ++d4)
      aq[d4] = *reinterpret_cast<const bf16x8*>(qrow + (d4 * 4 + lg) * 8);
  }
  __syncthreads();   // relk staged
  // qr = Q @ relk^T -> QR (own-wave rows)
#pragma unroll
  for (int rb = 0; rb < 3; ++rb) {
    f32x4 acc = {};
#pragma unroll
    for (int d4 = 0; d4 < 4; ++d4) {
      int rr = rb * 16 + ll;
      bf16x8 br = *reinterpret_cast<const bf16x8*>(KV + rr * 256 + (((d4 * 4 + lg) * 16) ^ ((rr & 7) << 4)));
      acc = __builtin_amdgcn_mfma_f32_16x16x32_bf16(aq[d4], br, acc, 0, 0, 0);
    }
    int col = rb * 16 + ll;
    if (col < 36)
#pragma unroll
      for (int e = 0; e < 4; ++e)
        QR[(w * 16 + lg * 4 + e) * 36 + col] = acc[e];
  }
  __syncthreads();   // all relk reads done
  { // write K(0) from regs
#pragma unroll
    for (int u = 0; u < 8; ++u) {
      int c = jhalf * 8 + u;
      *reinterpret_cast<uint4*>(KV + jrow * 256 + ((c * 16) ^ ((jrow & 7) << 4))) = kreg[u];
    }
  }
  __syncthreads();   // K(0) ready

  bool rowv[4];
#pragma unroll
  for (int e = 0; e < 4; ++e) rowv[e] = (i0 + w * 16 + lg * 4 + e) < len;

  float m_[4], ls_[4];
#pragma unroll
  for (int e = 0; e < 4; ++e) { m_[e] = -3.0e38f; ls_[e] = 0.f; }
  f32x4 oacc[8] = {};

  for (int kt = 0; kt < 4; ++kt) {
    // issue V(kt) -> regs (hidden under QK + softmax)
    uint4 vreg[8];
    {
      const u16* src = vt + (size_t)(hh * DHD + jrow) * TOK + b * SLEN + kt * 128;
#pragma unroll
      for (int u = 0; u < 8; ++u)
        vreg[u] = *reinterpret_cast<const uint4*>(src + (jhalf * 8 + u) * 8);
    }
    // QK^T
    __builtin_amdgcn_s_setprio(1);
    f32x4 sacc[8];
#pragma unroll
    for (int fj = 0; fj < 8; ++fj) {
      f32x4 a = {};
#pragma unroll
      for (int d4 = 0; d4 < 4; ++d4) {
        int row = fj * 16 + ll;
        bf16x8 bk_ = *reinterpret_cast<const bf16x8*>(KV + row * 256 + (((d4 * 4 + lg) * 16) ^ ((row & 7) << 4)));
        a = __builtin_amdgcn_mfma_f32_16x16x32_bf16(aq[d4], bk_, a, 0, 0, 0);
      }
      sacc[fj] = a;
    }
    __builtin_amdgcn_s_setprio(0);
    // fixup: + qr[rel] (rel from prefetched regs), scale, mask; tile max
    float pmax[4] = {-3.0e38f, -3.0e38f, -3.0e38f, -3.0e38f};
#pragma unroll
    for (int fj = 0; fj < 8; ++fj) {
      bool colv = (kt * 128 + fj * 16 + ll) < len;
      u32 rw = relw[fj];
#pragma unroll
      for (int e = 0; e < 4; ++e) {
        int r = (rw >> (8 * e)) & 255;
        float s = (sacc[fj][e] + QR[(w * 16 + lg * 4 + e) * 36 + r]) * scale;
        s = (rowv[e] && colv) ? s : -1e9f;
        sacc[fj][e] = s;
        pmax[e] = fmaxf(pmax[e], s);
      }
    }
#pragma unroll
    for (int e = 0; e < 4; ++e) {
      pmax[e] = fmaxf(pmax[e], __shfl_xor(pmax[e], 1, 64));
      pmax[e] = fmaxf(pmax[e], __shfl_xor(pmax[e], 2, 64));
      pmax[e] = fmaxf(pmax[e], __shfl_xor(pmax[e], 4, 64));
      pmax[e] = fmaxf(pmax[e], __shfl_xor(pmax[e], 8, 64));
    }
    float f_[4];
#pragma unroll
    for (int e = 0; e < 4; ++e) {
      float mn = fmaxf(m_[e], pmax[e]);
      f_[e] = __expf(m_[e] - mn);
      m_[e] = mn;
      ls_[e] *= f_[e];
    }
#pragma unroll
    for (int fd = 0; fd < 8; ++fd)
#pragma unroll
      for (int e = 0; e < 4; ++e) oacc[fd][e] *= f_[e];
#pragma unroll
    for (int e = 0; e < 4; ++e) {
      if (f_[e] != 1.0f) {
        int row = w * 16 + lg * 4 + e;
        AREL[row * 36 + ll] *= f_[e];
        AREL[row * 36 + 16 + ll] *= f_[e];
        if (ll == 0) AREL[row * 36 + 32] *= f_[e];
      }
    }
    // p = exp(s-m); accumulate l, AREL (r re-extracted from relw); stage P
    float psum[4] = {0.f, 0.f, 0.f, 0.f};
#pragma unroll
    for (int fj = 0; fj < 8; ++fj) {
      u32 rw = relw[fj];
#pragma unroll
      for (int e = 0; e < 4; ++e) {
        float p = __expf(sacc[fj][e] - m_[e]);
        psum[e] += p;
        int iloc = lg * 4 + e;
        atomicAdd(&AREL[(w * 16 + iloc) * 36 + ((rw >> (8 * e)) & 255)], p);
        *reinterpret_cast<u16*>(PSw + iloc * 256 + (((fj * 16 + ll) * 2) ^ ((iloc & 7) << 4))) = f2b(p);
      }
    }
#pragma unroll
    for (int e = 0; e < 4; ++e) {
      psum[e] += __shfl_xor(psum[e], 1, 64);
      psum[e] += __shfl_xor(psum[e], 2, 64);
      psum[e] += __shfl_xor(psum[e], 4, 64);
      psum[e] += __shfl_xor(psum[e], 8, 64);
      ls_[e] += psum[e];
    }
    // prefetch rel(kt+1)
    if (kt < 3) {
      const unsigned char* rb = relbase + (size_t)((kt + 1) * 128 + ll) * SLEN;
#pragma unroll
      for (int fj = 0; fj < 8; ++fj)
        relw[fj] = *reinterpret_cast<const u32*>(rb + (size_t)(fj * 16) * SLEN);
    }
    __syncthreads();            // all waves done reading K(kt)
    { // write V(kt) from regs
#pragma unroll
      for (int u = 0; u < 8; ++u) {
        int c = jhalf * 8 + u;
        *reinterpret_cast<uint4*>(KV + jrow * 256 + ((c * 16) ^ ((jrow & 7) << 4))) = vreg[u];
      }
    }
    __syncthreads();            // V ready
    // issue K(kt+1) -> regs (hidden under PV)
    if (kt < 3) {
      const u16* src = qk + (size_t)(b * SLEN + (kt + 1) * 128 + jrow) * 2048 + 1024 + hh * DHD;
#pragma unroll
      for (int u = 0; u < 8; ++u)
        kreg[u] = *reinterpret_cast<const uint4*>(src + (jhalf * 8 + u) * 8);
    }
    // PV
    __builtin_amdgcn_s_setprio(1);
#pragma unroll
    for (int kc = 0; kc < 4; ++kc) {
      bf16x8 pa = *reinterpret_cast<const bf16x8*>(PSw + ll * 256 + (((kc * 4 + lg) * 16) ^ ((ll & 7) << 4)));
#pragma unroll
      for (int fd = 0; fd < 8; ++fd) {
        int row = fd * 16 + ll;
        bf16x8 vb = *reinterpret_cast<const bf16x8*>(KV + row * 256 + (((kc * 4 + lg) * 16) ^ ((row & 7) << 4)));
        oacc[fd] = __builtin_amdgcn_mfma_f32_16x16x32_bf16(pa, vb, oacc[fd], 0, 0, 0);
      }
    }
    __builtin_amdgcn_s_setprio(0);
    __syncthreads();            // all waves done reading V(kt)
    if (kt < 3) {
      { // write K(kt+1)
#pragma unroll
        for (int u = 0; u < 8; ++u) {
          int c = jhalf * 8 + u;
          *reinterpret_cast<uint4*>(KV + jrow * 256 + ((c * 16) ^ ((jrow & 7) << 4))) = kreg[u];
        }
      }
      __syncthreads();          // K(kt+1) ready
    }
  }
  // ---- epilogue ----
#pragma unroll
  for (int e = 0; e < 4; ++e) {
    float inv = 1.0f / ls_[e];
#pragma unroll
    for (int fd = 0; fd < 8; ++fd) oacc[fd][e] *= inv;
  }
  if (ll == 0)
#pragma unroll
    for (int e = 0; e < 4; ++e) LSUM[w * 16 + lg * 4 + e] = ls_[e];
  // stage relv^T bf16 [128 d][64 r] swizzled into KV
  for (int idx = t; idx < 128 * 64; idx += 256) {
    int d = idx >> 6, r = idx & 63;
    u16 v = (r < RNUM) ? f2b(relv[r * DHD + d]) : (u16)0;
    *reinterpret_cast<u16*>(KV + d * 128 + ((r * 2) ^ ((d & 7) << 4))) = v;
  }
  // arelB = AREL/l bf16 [16][64] into own slab
  for (int idx = l; idx < 1024; idx += 64) {
    int ri = idx >> 6, r = idx & 63;
    int row = w * 16 + ri;
    float v = (r < RNUM) ? AREL[row * 36 + r] * (1.0f / LSUM[row]) : 0.f;
    *reinterpret_cast<u16*>(PSw + ri * 128 + ((r * 2) ^ ((ri & 7) << 4))) = f2b(v);
  }
  __syncthreads();              // relvT ready
#pragma unroll
  for (int kc = 0; kc < 2; ++kc) {
    bf16x8 pa = *reinterpret_cast<const bf16x8*>(PSw + ll * 128 + (((kc * 4 + lg) * 16) ^ ((ll & 7) << 4)));
#pragma unroll
    for (int fd = 0; fd < 8; ++fd) {
      int row = fd * 16 + ll;
      bf16x8 vb = *reinterpret_cast<const bf16x8*>(KV + row * 128 + (((kc * 4 + lg) * 16) ^ ((row & 7) << 4)));
      oacc[fd] = __builtin_amdgcn_mfma_f32_16x16x32_bf16(pa, vb, oacc[fd], 0, 0, 0);
    }
  }
#pragma unroll
  for (int fd = 0; fd < 8; ++fd)
#pragma unroll
    for (int e = 0; e < 4; ++e)
      *reinterpret_cast<u16*>(PSw + ((lg * 4 + e) * 128 + fd * 16 + ll) * 2) = f2b(oacc[fd][e]);
  __syncthreads();
  {
    int ri = l >> 2, q4 = l & 3;
    const char* srcb = PSw + ri * 256 + q4 * 64;
    u16* dst = outb + (size_t)(b * SLEN + i0 + w * 16 + ri) * EDIM + hh * DHD + q4 * 32;
    uint4 x0 = *reinterpret_cast<const uint4*>(srcb);
    uint4 x1 = *reinterpret_cast<const uint4*>(srcb + 16);
    uint4 x2 = *reinterpret_cast<const uint4*>(srcb + 32);
    uint4 x3 = *reinterpret_cast<const uint4*>(srcb + 48);
    *reinterpret_cast<uint4*>(dst)      = x0;
    *reinterpret_cast<uint4*>(dst + 8)  = x1;
    *reinterpret_cast<uint4*>(dst + 16) = x2;
    *reinterpret_cast<uint4*>(dst + 24) = x3;
  }
}

// ---------------- host ----------------
extern "C" void kernel_launch(void* const* d_in, const int* in_sizes, int n_in,
                              void* d_out, int out_size, void* d_ws, size_t ws_size,
                              hipStream_t stream) {
  const float* enc  = (const float*)d_in[0];
  const int*   rel  = (const int*)d_in[1];
  const int*   lens = (const int*)d_in[2];
  const float* Wq = (const float*)d_in[3];
  const float* bq = (const float*)d_in[4];
  const float* Wk = (const float*)d_in[5];
  const float* bk = (const float*)d_in[6];
  const float* Wv = (const float*)d_in[7];
  const float* bv = (const float*)d_in[8];
  const float* Wo = (const float*)d_in[9];
  const float* bo = (const float*)d_in[10];
  const float* relk = (const float*)d_in[11];
  const float* relv = (const float*)d_in[12];
  const float* W1 = (const float*)d_in[13];
  const float* b1 = (const float*)d_in[14];
  const float* W2 = (const float*)d_in[15];
  const float* b2 = (const float*)d_in[16];
  const float* ln1g = (const float*)d_in[17];
  const float* ln1b = (const float*)d_in[18];
  const float* ln2g = (const float*)d_in[19];
  const float* ln2b = (const float*)d_in[20];
  const float* lnfg = (const float*)d_in[21];
  const float* lnfb = (const float*)d_in[22];
  float* out = (float*)d_out;

  char* W = (char*)d_ws;
  u16* h     = (u16*)W;                                // 8 MB (dead during attn -> holds rel8)
  unsigned char* rel8 = (unsigned char*)W;             // 2.1 MB, rebuilt per layer
  char* U    = W + 8388608;
  u16* qkb   = (u16*)U;                                // 16 MB  [4096][2048]
  u16* vtb   = (u16*)(U + 16777216);                   // 8 MB   [1024][4096]
  u16* attno = (u16*)(U + 25165824);                   // 8 MB   [4096][1024]
  u16* mid   = (u16*)U;                                // 32 MB  (aliases qkb/vtb/attno)
  bool xin = ws_size >= (size_t)83886080;
  float* x = xin ? (float*)(W + 41943040) : out;
  char* WT = W + (xin ? 58720256 : 41943040);
  bool big = ws_size >= (size_t)209715200;

  const size_t EE = (size_t)EDIM * EDIM;      // 1M
  const size_t EF = (size_t)EDIM * FFD;       // 4M

  u16 *WqkT, *WvT, *WoT, *W1T, *W2T;
  dim3 blk(256);
  if (big) {
    u16* wqk_all = (u16*)WT;
    u16* wv_all  = wqk_all + 6 * 2 * EE;
    u16* wo_all  = wv_all + 6 * EE;
    u16* w1_all  = wo_all + 6 * EE;
    u16* w2_all  = w1_all + 6 * EF;
    wtrans<<<dim3(32, 32, 6), blk, 0, stream>>>(Wq, wqk_all, 1024, 1024, EE, 2 * EE);
    wtrans<<<dim3(32, 32, 6), blk, 0, stream>>>(Wk, wqk_all + EE, 1024, 1024, EE, 2 * EE);
    wtrans<<<dim3(32, 32, 6), blk, 0, stream>>>(Wv, wv_all, 1024, 1024, EE, EE);
    wtrans<<<dim3(32, 32, 6), blk, 0, stream>>>(Wo, wo_all, 1024, 1024, EE, EE);
    wtrans<<<dim3(128, 32, 6), blk, 0, stream>>>(W1, w1_all, 1024, 4096, EF, EF);
    wtrans<<<dim3(32, 128, 6), blk, 0, stream>>>(W2, w2_all, 4096, 1024, EF, EF);
    WqkT = wqk_all; WvT = wv_all; WoT = wo_all; W1T = w1_all; W2T = w2_all;
  } else {
    WqkT = (u16*)WT;
    WvT  = WqkT + 2 * EE;
    WoT  = WvT + EE;
    W1T  = WoT + EE;
    W2T  = W1T + EF;
  }

  dim3 gLN(TOK);
  for (int ll = 0; ll < LNUM; ++ll) {
    u16 *wqkT, *wvT, *woT, *w1T, *w2T;
    if (big) {
      wqkT = WqkT + (size_t)ll * 2 * EE; wvT = WvT + (size_t)ll * EE; woT = WoT + (size_t)ll * EE;
      w1T = W1T + (size_t)ll * EF; w2T = W2T + (size_t)ll * EF;
    } else {
      wqkT = WqkT; wvT = WvT; woT = WoT; w1T = W1T; w2T = W2T;
      wtrans<<<dim3(32, 32, 1), blk, 0, stream>>>(Wq + ll * EE, wqkT, 1024, 1024, 0, 0);
      wtrans<<<dim3(32, 32, 1), blk, 0, stream>>>(Wk + ll * EE, wqkT + EE, 1024, 1024, 0, 0);
      wtrans<<<dim3(32, 32, 1), blk, 0, stream>>>(Wv + ll * EE, wvT, 1024, 1024, 0, 0);
      wtrans<<<dim3(32, 32, 1), blk, 0, stream>>>(Wo + ll * EE, woT, 1024, 1024, 0, 0);
      wtrans<<<dim3(128, 32, 1), blk, 0, stream>>>(W1 + ll * EF, w1T, 1024, 4096, 0, 0);
      wtrans<<<dim3(32, 128, 1), blk, 0, stream>>>(W2 + ll * EF, w2T, 4096, 1024, 0, 0);
    }
    const float* xin_p = (ll == 0) ? enc : x;
    ln_kernel<1><<<gLN, blk, 0, stream>>>(xin_p, ln1g + ll * EDIM, ln1b + ll * EDIM, h);
    gemm_bt<2, 0, 0, 1><<<dim3(16, 32), blk, 0, stream>>>(h, wqkT, bq + ll * EDIM, bk + ll * EDIM,
                                                          nullptr, qkb, TOK, 2048, EDIM);
    gemm_bt<1, 0, 0, 1><<<dim3(32, 8), blk, 0, stream>>>(wvT, h, bv + ll * EDIM, nullptr,
                                                         nullptr, vtb, EDIM, TOK, EDIM);
    // h is dead now -> rebuild rel8 (u8 transposed) in its place
    relpack<<<dim3(16, 16, 8), blk, 0, stream>>>(rel, rel8);
    attn_kernel<<<dim3(512), blk, 0, stream>>>(qkb, vtb, rel8, lens,
                                               relk + (size_t)ll * RNUM * DHD,
                                               relv + (size_t)ll * RNUM * DHD, attno);
    gemm_bt<0, 0, 1, 0><<<dim3(8, 32), blk, 0, stream>>>(attno, woT, bo + ll * EDIM, nullptr,
                                                         xin_p, x, TOK, EDIM, EDIM);
    ln_kernel<1><<<gLN, blk, 0, stream>>>(x, ln2g + ll * EDIM, ln2b + ll * EDIM, h);
    gemm_bt<0, 1, 0, 1><<<dim3(32, 32), blk, 0, stream>>>(h, w1T, b1 + ll * FFD, nullptr,
                                                          nullptr, mid, TOK, FFD, EDIM);
    gemm_bt<0, 0, 1, 0><<<dim3(8, 32), blk, 0, stream>>>(mid, w2T, b2 + ll * EDIM, nullptr,
                                                         x, x, TOK, EDIM, FFD);
  }
  ln_kernel<0><<<gLN, blk, 0, stream>>>(x, lnfg, lnfb, out);
}

// Round 9
// 2296.221 us; speedup vs baseline: 1.2003x; 1.1141x over previous
//
#include <hip/hip_runtime.h>

#define LNUM 6
#define EDIM 1024
#define HNUM 8
#define DHD  128
#define RNUM 33
#define FFD  4096
#define BNUM 8
#define SLEN 512
#define TOK  (BNUM*SLEN)   // 4096

typedef __attribute__((ext_vector_type(8))) short bf16x8;
typedef __attribute__((ext_vector_type(4))) float f32x4;
typedef unsigned short u16;
typedef unsigned int u32;

__device__ __forceinline__ u16 f2b(float f) {
  u32 u = __builtin_bit_cast(u32, f);
  u32 r = u + 0x7FFFu + ((u >> 16) & 1u);
  return (u16)(r >> 16);
}
__device__ __forceinline__ u32 pck(float a, float b) { return (u32)f2b(a) | ((u32)f2b(b) << 16); }

// async global->LDS, 16B per lane. LDS dest is wave-uniform base + lane*16.
#define GL16(gp, lp) __builtin_amdgcn_global_load_lds(                        \
    (const __attribute__((address_space(1))) void*)(gp),                      \
    (__attribute__((address_space(3))) void*)(lp), 16, 0, 0)

// ---------------- LayerNorm ----------------
template<int BF16OUT>
__global__ __launch_bounds__(256) void ln_kernel(const float* __restrict__ x,
                                                 const float* __restrict__ g,
                                                 const float* __restrict__ be,
                                                 void* __restrict__ o) {
  int row = blockIdx.x;
  int t = threadIdx.x;
  const float* xr = x + (size_t)row * EDIM;
  float4 xv = *reinterpret_cast<const float4*>(xr + t * 4);
  float s1 = xv.x + xv.y + xv.z + xv.w;
  float s2 = xv.x*xv.x + xv.y*xv.y + xv.z*xv.z + xv.w*xv.w;
#pragma unroll
  for (int off = 32; off >= 1; off >>= 1) {
    s1 += __shfl_down(s1, off, 64);
    s2 += __shfl_down(s2, off, 64);
  }
  __shared__ float r1[4], r2[4];
  if ((t & 63) == 0) { r1[t >> 6] = s1; r2[t >> 6] = s2; }
  __syncthreads();
  s1 = r1[0] + r1[1] + r1[2] + r1[3];
  s2 = r2[0] + r2[1] + r2[2] + r2[3];
  float mean = s1 * (1.0f / EDIM);
  float var  = s2 * (1.0f / EDIM) - mean * mean;
  float rstd = rsqrtf(var + 1e-5f);
  float4 gv = *reinterpret_cast<const float4*>(g + t * 4);
  float4 bv = *reinterpret_cast<const float4*>(be + t * 4);
  float o0 = (xv.x - mean) * rstd * gv.x + bv.x;
  float o1 = (xv.y - mean) * rstd * gv.y + bv.y;
  float o2 = (xv.z - mean) * rstd * gv.z + bv.z;
  float o3 = (xv.w - mean) * rstd * gv.w + bv.w;
  if (BF16OUT) {
    ushort4 ov; ov.x = f2b(o0); ov.y = f2b(o1); ov.z = f2b(o2); ov.w = f2b(o3);
    *reinterpret_cast<ushort4*>((u16*)o + (size_t)row * EDIM + t * 4) = ov;
  } else {
    *reinterpret_cast<float4*>((float*)o + (size_t)row * EDIM + t * 4) = make_float4(o0, o1, o2, o3);
  }
}

// ---------------- Weight transpose: f32 [Kd][Nd] -> bf16 [Nd][Kd] ----------------
__global__ __launch_bounds__(256) void wtrans(const float* __restrict__ src0,
                                              u16* __restrict__ dst0,
                                              int Kd, int Nd, size_t sstride, size_t dstride) {
  __shared__ float Ts[32][33];
  const float* src = src0 + blockIdx.z * sstride;
  u16* dst = dst0 + blockIdx.z * dstride;
  int r0 = blockIdx.y * 32, c0 = blockIdx.x * 32;
  int ty = threadIdx.x >> 3, tx = threadIdx.x & 7;
  float4 v = *reinterpret_cast<const float4*>(src + (size_t)(r0 + ty) * Nd + c0 + tx * 4);
  Ts[ty][tx*4+0] = v.x; Ts[ty][tx*4+1] = v.y; Ts[ty][tx*4+2] = v.z; Ts[ty][tx*4+3] = v.w;
  __syncthreads();
  ushort4 o;
  o.x = f2b(Ts[tx*4+0][ty]); o.y = f2b(Ts[tx*4+1][ty]);
  o.z = f2b(Ts[tx*4+2][ty]); o.w = f2b(Ts[tx*4+3][ty]);
  *reinterpret_cast<ushort4*>(dst + (size_t)(c0 + ty) * Kd + r0 + tx * 4) = o;
}

// ---------------- rel pack+transpose: int32 [b][i][j] -> u8 [b][j][i] ----------------
__global__ __launch_bounds__(256) void relpack(const int* __restrict__ rel,
                                               unsigned char* __restrict__ out) {
  __shared__ int Ts[32][33];
  int bz = blockIdx.z;
  int r0 = blockIdx.y * 32, c0 = blockIdx.x * 32;
  int ty = threadIdx.x >> 3, tx = threadIdx.x & 7;
  const int* src = rel + (size_t)bz * SLEN * SLEN;
  int4 v = *reinterpret_cast<const int4*>(src + (size_t)(r0 + ty) * SLEN + c0 + tx * 4);
  Ts[ty][tx*4+0] = v.x; Ts[ty][tx*4+1] = v.y; Ts[ty][tx*4+2] = v.z; Ts[ty][tx*4+3] = v.w;
  __syncthreads();
  u32 o = (u32)(Ts[tx*4+0][ty] & 255) | ((u32)(Ts[tx*4+1][ty] & 255) << 8) |
          ((u32)(Ts[tx*4+2][ty] & 255) << 16) | ((u32)(Ts[tx*4+3][ty] & 255) << 24);
  *reinterpret_cast<u32*>(out + (size_t)bz * SLEN * SLEN + (size_t)(c0 + ty) * SLEN + r0 + tx * 4) = o;
}

// ---------------- bf16 MFMA GEMM: C[M,N] = A[M,K] @ B[N,K]^T ----------------
template<int BIASMODE, int ACT, int RES, int OUTBF16>
__global__ __launch_bounds__(256) void gemm_bt(const u16* __restrict__ A,
                                               const u16* __restrict__ B,
                                               const float* __restrict__ bias0,
                                               const float* __restrict__ bias1,
                                               const float* __restrict__ res,
                                               void* __restrict__ Cv,
                                               int M, int N, int K) {
  __shared__ u16 As[128 * 64];
  __shared__ u16 Bs[128 * 64];
  int t = threadIdx.x;
  int l = t & 63, w = t >> 6;
  int wm = w & 1, wn = w >> 1;
  int m0 = blockIdx.y * 128, n0 = blockIdx.x * 128;
  f32x4 acc[4][4] = {};
  const u16* Agp = A + (size_t)(m0 + w * 32 + (l >> 3)) * K + (l & 7) * 8;
  const u16* Bgp = B + (size_t)(n0 + w * 32 + (l >> 3)) * K + (l & 7) * 8;
  u16* Alp = As + w * 4 * 512;
  u16* Blp = Bs + w * 4 * 512;
  for (int k0 = 0; k0 < K; k0 += 64) {
    __syncthreads();
#pragma unroll
    for (int u = 0; u < 4; ++u) {
      GL16(Agp + (size_t)(u * 8) * K + k0, Alp + u * 512);
      GL16(Bgp + (size_t)(u * 8) * K + k0, Blp + u * 512);
    }
    __syncthreads();
#pragma unroll
    for (int d4 = 0; d4 < 2; ++d4) {
      bf16x8 af[4];
#pragma unroll
      for (int fm = 0; fm < 4; ++fm) {
        int row = wm * 64 + fm * 16 + (l & 15);
        af[fm] = *reinterpret_cast<const bf16x8*>(As + row * 64 + (d4 * 4 + (l >> 4)) * 8);
      }
#pragma unroll
      for (int fn = 0; fn < 4; ++fn) {
        int row = wn * 64 + fn * 16 + (l & 15);
        bf16x8 bf = *reinterpret_cast<const bf16x8*>(Bs + row * 64 + (d4 * 4 + (l >> 4)) * 8);
#pragma unroll
        for (int fm = 0; fm < 4; ++fm)
          acc[fm][fn] = __builtin_amdgcn_mfma_f32_16x16x32_bf16(af[fm], bf, acc[fm][fn], 0, 0, 0);
      }
    }
  }
#pragma unroll
  for (int fm = 0; fm < 4; ++fm)
#pragma unroll
    for (int fn = 0; fn < 4; ++fn)
#pragma unroll
      for (int e = 0; e < 4; ++e) {
        int m = m0 + wm * 64 + fm * 16 + (l >> 4) * 4 + e;
        int n = n0 + wn * 64 + fn * 16 + (l & 15);
        float v = acc[fm][fn][e];
        if (BIASMODE == 0) v += bias0[n];
        if (BIASMODE == 1) v += bias0[m];
        if (BIASMODE == 2) v += (n < 1024) ? bias0[n] : bias1[n - 1024];
        if (ACT == 1) v = fmaxf(v, 0.f);
        if (RES == 1) v += res[(size_t)m * N + n];
        if (OUTBF16) ((u16*)Cv)[(size_t)m * N + n] = f2b(v);
        else ((float*)Cv)[(size_t)m * N + n] = v;
      }
}

// ---------------- Relational attention (flash, GL16-pipelined, zero reg staging) ----
// Block = (b, h, 64 q-rows); wave w owns q-rows [w*16, w*16+16). 8 KV tiles of 64.
// K tiles live in buffer P, V tiles in buffer Q (fixed). Staging via global_load_lds
// with PRE-SWIZZLED global source + linear LDS dest (guide §5 rule 21 / m173).
// Loop uses raw s_barrier + counted s_waitcnt vmcnt(4) so prefetches stay in flight
// (T3/T4; __syncthreads would drain vmcnt->0 = the m97 stall). Cross-wave LDS in the
// loop is ONLY the P/Q tiles (guarded by vmcnt+barrier); QR/AREL/P-slab wave-private.
#define A_P  0        // 16384: relk[48][128] swz -> K tile [64][128] swz -> relvT [128][64]
#define A_Q  16384    // 16384: V tile [128 d][64 j] swz -> out-stage [4 waves][16][128]
#define A_PS 32768    // 8192 : per-wave 2048B slabs: P[16][64] swz / arelB [16][64]
#define A_QR 40960    // 9216 : qr f32 [64][36]
#define A_AR 50176    // 9216 : AREL f32 [64][36] (wave-private rows)
#define A_LS 59392    // 256  : LSUM f32 [64]
#define A_SM 59648

#define WAITVM4 do { asm volatile("s_waitcnt vmcnt(4)" ::: "memory"); \
                     __builtin_amdgcn_sched_barrier(0); } while (0)
#define WAITVM0 do { asm volatile("s_waitcnt vmcnt(0)" ::: "memory"); \
                     __builtin_amdgcn_sched_barrier(0); } while (0)

__global__ __launch_bounds__(256, 2) void attn_kernel(const u16* __restrict__ qk,
                                                      const u16* __restrict__ vt,
                                                      const unsigned char* __restrict__ rel8,
                                                      const int* __restrict__ lens,
                                                      const float* __restrict__ relk,
                                                      const float* __restrict__ relv,
                                                      u16* __restrict__ outb) {
  __align__(16) __shared__ char sm[A_SM];
  char*  Pb  = sm + A_P;
  char*  Qb  = sm + A_Q;
  char*  PSb = sm + A_PS;
  float* QR  = (float*)(sm + A_QR);
  float* AREL = (float*)(sm + A_AR);
  float* LSUM = (float*)(sm + A_LS);

  const int t = threadIdx.x;
  const int l = t & 63, w = t >> 6;
  const int lg = l >> 4;        // 0..3
  const int ll = l & 15;        // 0..15
  // XCD-aware mapping: all 8 q-tiles (it) of one (b,hh) share an XCD
  const int bx = blockIdx.x;
  const int xcd = bx & 7, rem = bx >> 3, slot = rem & 7, it = rem >> 3;
  const int g = slot * 8 + xcd;
  const int b = g >> 3, hh = g & 7;
  const int i0 = it * 64;
  const int len = lens[b];
  const float scale = 0.08838834764831845f;
  char* PSw = PSb + w * 2048;

  // ---- GL16 stagers: linear LDS dest, inverse-swizzled global source ----
  // K tile [64 rows j][256B] : chunk=w*4+u covers rows w*16+u*4.. ; lane -> row +l/16,
  // 16B slot l%16; source slot = (l%16) ^ (row&7).
  // V tile [128 rows d][128B]: chunk=w*4+u covers rows w*32+u*8.. ; lane -> row +l/8,
  // 16B slot l%8; source slot = (l%8) ^ (row&7), row&7 = l/8.
  auto issueK = [&](int kt) {
#pragma unroll
    for (int u = 0; u < 4; ++u) {
      int row = w * 16 + u * 4 + (lg);                 // lg = l>>4
      int sb = (ll * 16) ^ (((u * 4 + lg) & 7) << 4);
      const u16* gp = qk + (size_t)(b * SLEN + kt * 64 + row) * 2048 + 1024 + hh * DHD + (sb >> 1);
      GL16(gp, Pb + (w * 4 + u) * 1024);
    }
  };
  auto issueV = [&](int kt) {
#pragma unroll
    for (int u = 0; u < 4; ++u) {
      int row = w * 32 + u * 8 + (l >> 3);
      int sb = ((l & 7) * 16) ^ ((l >> 3) << 4);
      const u16* gp = vt + (size_t)(hh * DHD + row) * TOK + b * SLEN + kt * 64 + (sb >> 1);
      GL16(gp, Qb + (w * 4 + u) * 1024);
    }
  };

  // ---- prologue ----
  u32 relw[4];
  const unsigned char* relbase = rel8 + (size_t)b * SLEN * SLEN + (i0 + w * 16 + lg * 4);
  {
    const unsigned char* rb = relbase + (size_t)ll * SLEN;
#pragma unroll
    for (int fj = 0; fj < 4; ++fj)
      relw[fj] = *reinterpret_cast<const u32*>(rb + (size_t)(fj * 16) * SLEN);
  }
  for (int idx = l; idx < 16 * 36; idx += 64) AREL[w * 16 * 36 + idx] = 0.f;
  // stage relk bf16 [48][128] swizzled into P
  if (t < 192) {
    int r = t >> 2, sub = t & 3;
#pragma unroll
    for (int u = 0; u < 4; ++u) {
      int seg = sub * 4 + u;
      uint4 o;
      if (r < RNUM) {
        float4 f0 = *reinterpret_cast<const float4*>(relk + r * DHD + seg * 8);
        float4 f1 = *reinterpret_cast<const float4*>(relk + r * DHD + seg * 8 + 4);
        o.x = pck(f0.x, f0.y); o.y = pck(f0.z, f0.w);
        o.z = pck(f1.x, f1.y); o.w = pck(f1.z, f1.w);
      } else { o.x = o.y = o.z = o.w = 0u; }
      *reinterpret_cast<uint4*>(Pb + r * 256 + ((seg * 16) ^ ((r & 7) << 4))) = o;
    }
  }
  // Q fragments (global -> reg)
  bf16x8 aq[4];
  {
    const u16* qrow = qk + (size_t)(b * SLEN + i0 + w * 16 + ll) * 2048 + hh * DHD;
#pragma unroll
    for (int d4 = 0; d4 < 4; ++d4)
      aq[d4] = *reinterpret_cast<const bf16x8*>(qrow + (d4 * 4 + lg) * 8);
  }
  __syncthreads();   // relk staged (full sync ok in prologue)
  // qr = Q @ relk^T -> QR (own-wave rows)
#pragma unroll
  for (int rb = 0; rb < 3; ++rb) {
    f32x4 acc = {};
#pragma unroll
    for (int d4 = 0; d4 < 4; ++d4) {
      int rr = rb * 16 + ll;
      bf16x8 br = *reinterpret_cast<const bf16x8*>(Pb + rr * 256 + (((d4 * 4 + lg) * 16) ^ ((rr & 7) << 4)));
      acc = __builtin_amdgcn_mfma_f32_16x16x32_bf16(aq[d4], br, acc, 0, 0, 0);
    }
    int col = rb * 16 + ll;
    if (col < 36)
#pragma unroll
      for (int e = 0; e < 4; ++e)
        QR[(w * 16 + lg * 4 + e) * 36 + col] = acc[e];
  }
  __syncthreads();   // all relk reads done; P free
  issueK(0);         // K(0) in flight (oldest)

  bool rowv[4];
#pragma unroll
  for (int e = 0; e < 4; ++e) rowv[e] = (i0 + w * 16 + lg * 4 + e) < len;

  float m_[4], ls_[4];
#pragma unroll
  for (int e = 0; e < 4; ++e) { m_[e] = -3.0e38f; ls_[e] = 0.f; }
  f32x4 oacc[8] = {};

  for (int kt = 0; kt < 8; ++kt) {
    issueV(kt);                 // -> Q (prev PV readers done at loop-end barrier)
    WAITVM4;                    // K(kt) landed; V(kt)'s 4 still flying
    __builtin_amdgcn_s_barrier();
    // QK^T on P: 16 q-rows x 64 keys per wave
    __builtin_amdgcn_s_setprio(1);
    f32x4 sacc[4];
#pragma unroll
    for (int fj = 0; fj < 4; ++fj) {
      f32x4 a = {};
#pragma unroll
      for (int d4 = 0; d4 < 4; ++d4) {
        int row = fj * 16 + ll;
        bf16x8 bk_ = *reinterpret_cast<const bf16x8*>(Pb + row * 256 + (((d4 * 4 + lg) * 16) ^ ((row & 7) << 4)));
        a = __builtin_amdgcn_mfma_f32_16x16x32_bf16(aq[d4], bk_, a, 0, 0, 0);
      }
      sacc[fj] = a;
    }
    __builtin_amdgcn_s_setprio(0);
    // fixup + online softmax
    float pmax[4] = {-3.0e38f, -3.0e38f, -3.0e38f, -3.0e38f};
#pragma unroll
    for (int fj = 0; fj < 4; ++fj) {
      bool colv = (kt * 64 + fj * 16 + ll) < len;
      u32 rw = relw[fj];
#pragma unroll
      for (int e = 0; e < 4; ++e) {
        int r = (rw >> (8 * e)) & 255;
        float s = (sacc[fj][e] + QR[(w * 16 + lg * 4 + e) * 36 + r]) * scale;
        s = (rowv[e] && colv) ? s : -1e9f;
        sacc[fj][e] = s;
        pmax[e] = fmaxf(pmax[e], s);
      }
    }
#pragma unroll
    for (int e = 0; e < 4; ++e) {
      pmax[e] = fmaxf(pmax[e], __shfl_xor(pmax[e], 1, 64));
      pmax[e] = fmaxf(pmax[e], __shfl_xor(pmax[e], 2, 64));
      pmax[e] = fmaxf(pmax[e], __shfl_xor(pmax[e], 4, 64));
      pmax[e] = fmaxf(pmax[e], __shfl_xor(pmax[e], 8, 64));
    }
    float f_[4];
#pragma unroll
    for (int e = 0; e < 4; ++e) {
      float mn = fmaxf(m_[e], pmax[e]);
      f_[e] = __expf(m_[e] - mn);
      m_[e] = mn;
      ls_[e] *= f_[e];
    }
#pragma unroll
    for (int fd = 0; fd < 8; ++fd)
#pragma unroll
      for (int e = 0; e < 4; ++e) oacc[fd][e] *= f_[e];
#pragma unroll
    for (int e = 0; e < 4; ++e) {
      if (f_[e] != 1.0f) {
        int row = w * 16 + lg * 4 + e;
        AREL[row * 36 + ll] *= f_[e];
        AREL[row * 36 + 16 + ll] *= f_[e];
        if (ll == 0) AREL[row * 36 + 32] *= f_[e];
      }
    }
    float psum[4] = {0.f, 0.f, 0.f, 0.f};
#pragma unroll
    for (int fj = 0; fj < 4; ++fj) {
      u32 rw = relw[fj];
#pragma unroll
      for (int e = 0; e < 4; ++e) {
        float p = __expf(sacc[fj][e] - m_[e]);
        psum[e] += p;
        int iloc = lg * 4 + e;
        atomicAdd(&AREL[(w * 16 + iloc) * 36 + ((rw >> (8 * e)) & 255)], p);
        *reinterpret_cast<u16*>(PSw + iloc * 128 + (((fj * 16 + ll) * 2) ^ ((iloc & 7) << 4))) = f2b(p);
      }
    }
#pragma unroll
    for (int e = 0; e < 4; ++e) {
      psum[e] += __shfl_xor(psum[e], 1, 64);
      psum[e] += __shfl_xor(psum[e], 2, 64);
      psum[e] += __shfl_xor(psum[e], 4, 64);
      psum[e] += __shfl_xor(psum[e], 8, 64);
      ls_[e] += psum[e];
    }
    if (kt < 7) {   // prefetch rel(kt+1) into regs
      const unsigned char* rb = relbase + (size_t)((kt + 1) * 64 + ll) * SLEN;
#pragma unroll
      for (int fj = 0; fj < 4; ++fj)
        relw[fj] = *reinterpret_cast<const u32*>(rb + (size_t)(fj * 16) * SLEN);
    }
    __builtin_amdgcn_s_barrier();   // all waves done reading K(kt) from P
    if (kt < 7) issueK(kt + 1);     // -> P (in flight across PV)
    if (kt < 7) { WAITVM4; } else { WAITVM0; }   // V(kt) landed
    __builtin_amdgcn_s_barrier();
    // PV on Q
    __builtin_amdgcn_s_setprio(1);
#pragma unroll
    for (int kc = 0; kc < 2; ++kc) {
      bf16x8 pa = *reinterpret_cast<const bf16x8*>(PSw + ll * 128 + (((kc * 4 + lg) * 16) ^ ((ll & 7) << 4)));
#pragma unroll
      for (int fd = 0; fd < 8; ++fd) {
        int row = fd * 16 + ll;
        bf16x8 vb = *reinterpret_cast<const bf16x8*>(Qb + row * 128 + (((kc * 4 + lg) * 16) ^ ((row & 7) << 4)));
        oacc[fd] = __builtin_amdgcn_mfma_f32_16x16x32_bf16(pa, vb, oacc[fd], 0, 0, 0);
      }
    }
    __builtin_amdgcn_s_setprio(0);
    __builtin_amdgcn_s_barrier();   // all waves done reading V(kt) (before next issueV)
  }
  // ---- epilogue (no loads in flight; full syncs ok) ----
#pragma unroll
  for (int e = 0; e < 4; ++e) {
    float inv = 1.0f / ls_[e];
#pragma unroll
    for (int fd = 0; fd < 8; ++fd) oacc[fd][e] *= inv;
  }
  if (ll == 0)
#pragma unroll
    for (int e = 0; e < 4; ++e) LSUM[w * 16 + lg * 4 + e] = ls_[e];
  // stage relv^T bf16 [128 d][64 r] swizzled into P (128B rows)
  for (int idx = t; idx < 128 * 64; idx += 256) {
    int d = idx >> 6, r = idx & 63;
    u16 v = (r < RNUM) ? f2b(relv[r * DHD + d]) : (u16)0;
    *reinterpret_cast<u16*>(Pb + d * 128 + ((r * 2) ^ ((d & 7) << 4))) = v;
  }
  // arelB = AREL/l bf16 [16][64] into own slab
  for (int idx = l; idx < 1024; idx += 64) {
    int ri = idx >> 6, r = idx & 63;
    int row = w * 16 + ri;
    float v = (r < RNUM) ? AREL[row * 36 + r] * (1.0f / LSUM[row]) : 0.f;
    *reinterpret_cast<u16*>(PSw + ri * 128 + ((r * 2) ^ ((ri & 7) << 4))) = f2b(v);
  }
  __syncthreads();              // relvT ready
#pragma unroll
  for (int kc = 0; kc < 2; ++kc) {
    bf16x8 pa = *reinterpret_cast<const bf16x8*>(PSw + ll * 128 + (((kc * 4 + lg) * 16) ^ ((ll & 7) << 4)));
#pragma unroll
    for (int fd = 0; fd < 8; ++fd) {
      int row = fd * 16 + ll;
      bf16x8 vb = *reinterpret_cast<const bf16x8*>(Pb + row * 128 + (((kc * 4 + lg) * 16) ^ ((row & 7) << 4)));
      oacc[fd] = __builtin_amdgcn_mfma_f32_16x16x32_bf16(pa, vb, oacc[fd], 0, 0, 0);
    }
  }
  // out-stage [16][128] linear in own 4KB slab of Q, then coalesced store
  char* OSw = Qb + w * 4096;
#pragma unroll
  for (int fd = 0; fd < 8; ++fd)
#pragma unroll
    for (int e = 0; e < 4; ++e)
      *reinterpret_cast<u16*>(OSw + ((lg * 4 + e) * 128 + fd * 16 + ll) * 2) = f2b(oacc[fd][e]);
  __syncthreads();
  {
    int ri = l >> 2, q4 = l & 3;
    const char* srcb = OSw + ri * 256 + q4 * 64;
    u16* dst = outb + (size_t)(b * SLEN + i0 + w * 16 + ri) * EDIM + hh * DHD + q4 * 32;
    uint4 x0 = *reinterpret_cast<const uint4*>(srcb);
    uint4 x1 = *reinterpret_cast<const uint4*>(srcb + 16);
    uint4 x2 = *reinterpret_cast<const uint4*>(srcb + 32);
    uint4 x3 = *reinterpret_cast<const uint4*>(srcb + 48);
    *reinterpret_cast<uint4*>(dst)      = x0;
    *reinterpret_cast<uint4*>(dst + 8)  = x1;
    *reinterpret_cast<uint4*>(dst + 16) = x2;
    *reinterpret_cast<uint4*>(dst + 24) = x3;
  }
}

// ---------------- host ----------------
extern "C" void kernel_launch(void* const* d_in, const int* in_sizes, int n_in,
                              void* d_out, int out_size, void* d_ws, size_t ws_size,
                              hipStream_t stream) {
  const float* enc  = (const float*)d_in[0];
  const int*   rel  = (const int*)d_in[1];
  const int*   lens = (const int*)d_in[2];
  const float* Wq = (const float*)d_in[3];
  const float* bq = (const float*)d_in[4];
  const float* Wk = (const float*)d_in[5];
  const float* bk = (const float*)d_in[6];
  const float* Wv = (const float*)d_in[7];
  const float* bv = (const float*)d_in[8];
  const float* Wo = (const float*)d_in[9];
  const float* bo = (const float*)d_in[10];
  const float* relk = (const float*)d_in[11];
  const float* relv = (const float*)d_in[12];
  const float* W1 = (const float*)d_in[13];
  const float* b1 = (const float*)d_in[14];
  const float* W2 = (const float*)d_in[15];
  const float* b2 = (const float*)d_in[16];
  const float* ln1g = (const float*)d_in[17];
  const float* ln1b = (const float*)d_in[18];
  const float* ln2g = (const float*)d_in[19];
  const float* ln2b = (const float*)d_in[20];
  const float* lnfg = (const float*)d_in[21];
  const float* lnfb = (const float*)d_in[22];
  float* out = (float*)d_out;

  char* W = (char*)d_ws;
  u16* h     = (u16*)W;                                // 8 MB (dead during attn -> holds rel8)
  unsigned char* rel8 = (unsigned char*)W;             // 2.1 MB, rebuilt per layer
  char* U    = W + 8388608;
  u16* qkb   = (u16*)U;                                // 16 MB  [4096][2048]
  u16* vtb   = (u16*)(U + 16777216);                   // 8 MB   [1024][4096]
  u16* attno = (u16*)(U + 25165824);                   // 8 MB   [4096][1024]
  u16* mid   = (u16*)U;                                // 32 MB  (aliases qkb/vtb/attno)
  bool xin = ws_size >= (size_t)83886080;
  float* x = xin ? (float*)(W + 41943040) : out;
  char* WT = W + (xin ? 58720256 : 41943040);
  bool big = ws_size >= (size_t)209715200;

  const size_t EE = (size_t)EDIM * EDIM;      // 1M
  const size_t EF = (size_t)EDIM * FFD;       // 4M

  u16 *WqkT, *WvT, *WoT, *W1T, *W2T;
  dim3 blk(256);
  if (big) {
    u16* wqk_all = (u16*)WT;
    u16* wv_all  = wqk_all + 6 * 2 * EE;
    u16* wo_all  = wv_all + 6 * EE;
    u16* w1_all  = wo_all + 6 * EE;
    u16* w2_all  = w1_all + 6 * EF;
    wtrans<<<dim3(32, 32, 6), blk, 0, stream>>>(Wq, wqk_all, 1024, 1024, EE, 2 * EE);
    wtrans<<<dim3(32, 32, 6), blk, 0, stream>>>(Wk, wqk_all + EE, 1024, 1024, EE, 2 * EE);
    wtrans<<<dim3(32, 32, 6), blk, 0, stream>>>(Wv, wv_all, 1024, 1024, EE, EE);
    wtrans<<<dim3(32, 32, 6), blk, 0, stream>>>(Wo, wo_all, 1024, 1024, EE, EE);
    wtrans<<<dim3(128, 32, 6), blk, 0, stream>>>(W1, w1_all, 1024, 4096, EF, EF);
    wtrans<<<dim3(32, 128, 6), blk, 0, stream>>>(W2, w2_all, 4096, 1024, EF, EF);
    WqkT = wqk_all; WvT = wv_all; WoT = wo_all; W1T = w1_all; W2T = w2_all;
  } else {
    WqkT = (u16*)WT;
    WvT  = WqkT + 2 * EE;
    WoT  = WvT + EE;
    W1T  = WoT + EE;
    W2T  = W1T + EF;
  }

  dim3 gLN(TOK);
  for (int ll = 0; ll < LNUM; ++ll) {
    u16 *wqkT, *wvT, *woT, *w1T, *w2T;
    if (big) {
      wqkT = WqkT + (size_t)ll * 2 * EE; wvT = WvT + (size_t)ll * EE; woT = WoT + (size_t)ll * EE;
      w1T = W1T + (size_t)ll * EF; w2T = W2T + (size_t)ll * EF;
    } else {
      wqkT = WqkT; wvT = WvT; woT = WoT; w1T = W1T; w2T = W2T;
      wtrans<<<dim3(32, 32, 1), blk, 0, stream>>>(Wq + ll * EE, wqkT, 1024, 1024, 0, 0);
      wtrans<<<dim3(32, 32, 1), blk, 0, stream>>>(Wk + ll * EE, wqkT + EE, 1024, 1024, 0, 0);
      wtrans<<<dim3(32, 32, 1), blk, 0, stream>>>(Wv + ll * EE, wvT, 1024, 1024, 0, 0);
      wtrans<<<dim3(32, 32, 1), blk, 0, stream>>>(Wo + ll * EE, woT, 1024, 1024, 0, 0);
      wtrans<<<dim3(128, 32, 1), blk, 0, stream>>>(W1 + ll * EF, w1T, 1024, 4096, 0, 0);
      wtrans<<<dim3(32, 128, 1), blk, 0, stream>>>(W2 + ll * EF, w2T, 4096, 1024, 0, 0);
    }
    const float* xin_p = (ll == 0) ? enc : x;
    ln_kernel<1><<<gLN, blk, 0, stream>>>(xin_p, ln1g + ll * EDIM, ln1b + ll * EDIM, h);
    gemm_bt<2, 0, 0, 1><<<dim3(16, 32), blk, 0, stream>>>(h, wqkT, bq + ll * EDIM, bk + ll * EDIM,
                                                          nullptr, qkb, TOK, 2048, EDIM);
    gemm_bt<1, 0, 0, 1><<<dim3(32, 8), blk, 0, stream>>>(wvT, h, bv + ll * EDIM, nullptr,
                                                         nullptr, vtb, EDIM, TOK, EDIM);
    // h is dead now -> rebuild rel8 (u8 transposed) in its place
    relpack<<<dim3(16, 16, 8), blk, 0, stream>>>(rel, rel8);
    attn_kernel<<<dim3(512), blk, 0, stream>>>(qkb, vtb, rel8, lens,
                                               relk + (size_t)ll * RNUM * DHD,
                                               relv + (size_t)ll * RNUM * DHD, attno);
    gemm_bt<0, 0, 1, 0><<<dim3(8, 32), blk, 0, stream>>>(attno, woT, bo + ll * EDIM, nullptr,
                                                         xin_p, x, TOK, EDIM, EDIM);
    ln_kernel<1><<<gLN, blk, 0, stream>>>(x, ln2g + ll * EDIM, ln2b + ll * EDIM, h);
    gemm_bt<0, 1, 0, 1><<<dim3(32, 32), blk, 0, stream>>>(h, w1T, b1 + ll * FFD, nullptr,
                                                          nullptr, mid, TOK, FFD, EDIM);
    gemm_bt<0, 0, 1, 0><<<dim3(8, 32), blk, 0, stream>>>(mid, w2T, b2 + ll * EDIM, nullptr,
                                                         x, x, TOK, EDIM, FFD);
  }
  ln_kernel<0><<<gLN, blk, 0, stream>>>(x, lnfg, lnfb, out);
}